// Round 24
// baseline (2084.851 us; speedup 1.0000x reference)
//
#include <hip/hip_runtime.h>

#define T_ 8192
#define B_ 4

typedef _Float16 h16;
typedef _Float16 half8 __attribute__((ext_vector_type(8)));
typedef float    f32x4 __attribute__((ext_vector_type(4)));

__device__ __forceinline__ void split2(float v, h16* hp, h16* lp) {
  h16 h = (h16)v; *hp = h; *lp = (h16)(v - (float)h);
}
__device__ __forceinline__ float join2(h16 h, h16 l) {
  return (float)h + (float)l;
}
__device__ __forceinline__ void gl2lds16(const void* g, void* l) {
  __builtin_amdgcn_global_load_lds(
      (const __attribute__((address_space(1))) unsigned int*)g,
      (__attribute__((address_space(3))) unsigned int*)l, 16, 0, 0);
}

// ============================================================================
// init/fs: channel c of input projection -> small planes (B,T,64)
// ============================================================================
__global__ __launch_bounds__(256) void init_fs_k(
    const float* __restrict__ x, const float* __restrict__ cw,
    const float* __restrict__ cb, h16* __restrict__ sh, h16* __restrict__ sl,
    int c)
{
  size_t idx = (size_t)blockIdx.x * 256 + threadIdx.x;   // over B*T*64
  int n = (int)(idx & 63);
  int t = (int)((idx >> 6) & (T_ - 1));
  int b = (int)(idx >> 19);
  float x0 = x[(((size_t)b*3 + 0)*T_ + t)*64 + n];
  float x1 = x[(((size_t)b*3 + 1)*T_ + t)*64 + n];
  float x2 = x[(((size_t)b*3 + 2)*T_ + t)*64 + n];
  float v = cb[c] + x0*cw[c*3] + x1*cw[c*3+1] + x2*cw[c*3+2];
  split2(v, &sh[idx], &sl[idx]);
}

__global__ __launch_bounds__(256) void wsplit_k(
    const float* __restrict__ src, h16* __restrict__ dh, h16* __restrict__ dl,
    int n)
{
  int i = blockIdx.x*256 + threadIdx.x;
  if (i < n) split2(src[i], &dh[i], &dl[i]);
}

// out_w (48x256) -> padded 64x256 planes
__global__ __launch_bounds__(256) void wsplit_out_k(
    const float* __restrict__ src, h16* __restrict__ dh, h16* __restrict__ dl)
{
  int i = blockIdx.x*256 + threadIdx.x;   // 0..16383
  int row = i >> 8;
  float v = (row < 48) ? src[i] : 0.f;
  split2(v, &dh[i], &dl[i]);
}

// ============================================================================
// Per-layer prep (hi-only weights): conv W transpose, W2 = co_w@ow into Wcat
// left half, Wco right half, bias3, stats zero. grid 1289.
// ============================================================================
__global__ __launch_bounds__(256) void prep_layer_k(
    const float* __restrict__ ffw, const float* __restrict__ cow,
    const float* __restrict__ ow, const float* __restrict__ ob,
    const float* __restrict__ cob,
    h16* __restrict__ dh,
    float* __restrict__ bias3, float* __restrict__ stats)
{
  int blk = blockIdx.x, tid = threadIdx.x;
  if (blk < 1024) {
    int i = blk*256 + tid;     // 0..262143
    if (i < 196608) {
      int tap = i >> 16, nk = i & 65535;
      dh[i] = (h16)ffw[(size_t)nk*3 + tap];
    } else {
      int e = i - 196608;
      int n = e >> 8, k = e & 255;
      dh[196608 + n*512 + 256 + k] = (h16)cow[e];
    }
  } else if (blk < 1280) {
    int n = blk - 1024;
    __shared__ float Ar[256];
    int k = tid;
    Ar[k] = cow[n*256 + k];
    __syncthreads();
    float acc = 0.f;
    #pragma unroll 4
    for (int j = 0; j < 256; ++j) acc = fmaf(Ar[j], ow[j*256 + k], acc);
    dh[196608 + n*512 + k] = (h16)acc;
  } else if (blk == 1280) {
    int n = tid;
    float s = cob[n];
    #pragma unroll 4
    for (int j = 0; j < 256; ++j) s = fmaf(cow[n*256 + j], ob[j], s);
    bias3[n] = s;
  } else {
    stats[(blk - 1281)*256 + tid] = 0.f;
  }
}

// per-SFI weight prep: ff1(65536) + ff2(65536) + cs(16384)  (hi/lo)
__global__ __launch_bounds__(256) void sprep_k(
    const float* __restrict__ f1, const float* __restrict__ f2,
    const float* __restrict__ cs, h16* __restrict__ dh, h16* __restrict__ dl)
{
  int i = blockIdx.x*256 + threadIdx.x;   // 0..147455
  float v = (i < 65536) ? f1[i] : (i < 131072) ? f2[i-65536] : cs[i-131072];
  split2(v, &dh[i], &dl[i]);
}

// ============================================================================
// Fused norm-folded QKV weight (hi only) + bias prep. grid 3840.
// ============================================================================
__global__ __launch_bounds__(256) void nwnb_k(
    const float* __restrict__ qw, const float* __restrict__ kw,
    const float* __restrict__ vw,
    const float* __restrict__ qb, const float* __restrict__ kb,
    const float* __restrict__ vb,
    const float* __restrict__ stats,
    h16* __restrict__ dh, float* __restrict__ bias2)
{
  int blk = blockIdx.x, tid = threadIdx.x;
  if (blk < 3072) {
    int i = blk*256 + tid;     // 0..786431
    int k = i & 255;
    int b = (i >> 16) & 3;
    int sel = i >> 18;
    float sm = stats[b*512 + k] * (1.f/T_);
    float s2 = stats[b*512 + 256 + k] * (1.f/T_);
    float iv = rsqrtf(fmaxf(s2 - sm*sm, 0.f) + 1e-5f);
    const float* w = sel == 0 ? kw : sel == 1 ? vw : qw;
    dh[i] = (h16)(w[i & 65535] * iv);
  } else {
    int base = (blk - 3072) * 4;
    int g = tid >> 6, l = tid & 63;
    int id = base + g;                     // sel*1024 + b*256 + n
    int n = id & 255, b = (id >> 8) & 3, sel = id >> 10;
    const float* w  = sel == 0 ? kw : sel == 1 ? vw : qw;
    const float* bb = sel == 0 ? kb : sel == 1 ? vb : qb;
    float s = 0.f;
    #pragma unroll
    for (int j = 0; j < 4; ++j) {
      int k = l*4 + j;
      float sm = stats[b*512 + k] * (1.f/T_);
      float s2 = stats[b*512 + 256 + k] * (1.f/T_);
      float iv = rsqrtf(fmaxf(s2 - sm*sm, 0.f) + 1e-5f);
      s += sm * iv * w[n*256 + k];
    }
    #pragma unroll
    for (int off = 32; off > 0; off >>= 1) s += __shfl_xor(s, off);
    if (l == 0) bias2[id] = bb[n] - s;
  }
}

// wf[bb][n,k] = sum_j ff1[n,j]*G[bb][j,k] + ff1[n,k]  -> hi-only plane.
__global__ __launch_bounds__(256) void mmrow_k(
    const float* __restrict__ A, const float* __restrict__ Bm,
    h16* __restrict__ dh)
{
  int n  = blockIdx.x & 255;
  int bb = blockIdx.x >> 8;
  __shared__ float Ar[256];
  int k = threadIdx.x;
  Ar[k] = A[n*256 + k];
  __syncthreads();
  const float* Bb = Bm + (size_t)bb*65536;
  float acc = 0.f;
  #pragma unroll 4
  for (int j = 0; j < 256; ++j) acc = fmaf(Ar[j], Bb[j*256 + k], acc);
  acc += Ar[k];
  dh[(size_t)bb*65536 + (size_t)n*256 + k] = (h16)acc;
}

// ============================================================================
// Pre-split fp16x2 MFMA GEMM, tile 128x128 (dual-A, dual-W, 3 MFMA).
// SGL=1: single-fp16 output. (r17-proven template.)
// ============================================================================
template<int ACT, int SGL>
__global__ __launch_bounds__(256, 2) void gemm_p(
    const h16* __restrict__ Agh, const h16* __restrict__ Agl,
    const h16* __restrict__ Wgh, const h16* __restrict__ Wgl,
    const float* __restrict__ bias,
    const h16* __restrict__ Rh, const h16* __restrict__ Rl,
    h16* __restrict__ Ch, h16* __restrict__ Cl,
    int K, size_t wbs)
{
  int b  = blockIdx.z;
  int n0 = blockIdx.x * 128;
  int t0 = blockIdx.y * 128;
  const h16* Ah_g = Agh + (size_t)b*T_*K;
  const h16* Al_g = Agl + (size_t)b*T_*K;
  const h16* Wh_g = Wgh + (size_t)b*wbs;
  const h16* Wl_g = Wgl + (size_t)b*wbs;
  __shared__ h16 S[16384];
  int tid = threadIdx.x, l = tid & 63, wid = tid >> 6;
  int wr = wid >> 1, wc = wid & 1, lr = l & 15, kg = l >> 4;
  f32x4 acc[4][4];
  #pragma unroll
  for (int m = 0; m < 4; ++m)
    #pragma unroll
    for (int n = 0; n < 4; ++n) acc[m][n] = (f32x4){0.f,0.f,0.f,0.f};

  for (int k0 = 0; k0 < K; k0 += 32) {
    #pragma unroll
    for (int i = 0; i < 8; ++i) {
      int c = i*256 + tid;
      int p = c >> 9, r = (c >> 2) & 127, kc = c & 3;
      int ks = k0 + ((kc ^ ((r >> 1) & 3)) << 3);
      const h16* src = (p == 0) ? Ah_g + (size_t)(t0 + r)*K + ks
                     : (p == 1) ? Al_g + (size_t)(t0 + r)*K + ks
                     : (p == 2) ? Wh_g + (size_t)(n0 + r)*K + ks
                                : Wl_g + (size_t)(n0 + r)*K + ks;
      gl2lds16(src, S + (size_t)c*8);
    }
    __syncthreads();
    half8 ah[4], al[4], wh[4], wl[4];
    #pragma unroll
    for (int m = 0; m < 4; ++m) {
      int row = wr*64 + m*16 + lr;
      int ko = (kg ^ ((row >> 1) & 3)) * 8;
      ah[m] = *(const half8*)&S[row*32 + ko];
      al[m] = *(const half8*)&S[4096 + row*32 + ko];
    }
    #pragma unroll
    for (int n = 0; n < 4; ++n) {
      int row = wc*64 + n*16 + lr;
      int ko = (kg ^ ((row >> 1) & 3)) * 8;
      wh[n] = *(const half8*)&S[8192 + row*32 + ko];
      wl[n] = *(const half8*)&S[12288 + row*32 + ko];
    }
    #pragma unroll
    for (int m = 0; m < 4; ++m)
      #pragma unroll
      for (int n = 0; n < 4; ++n) {
        acc[m][n] = __builtin_amdgcn_mfma_f32_16x16x32_f16(ah[m], wh[n], acc[m][n], 0, 0, 0);
        acc[m][n] = __builtin_amdgcn_mfma_f32_16x16x32_f16(al[m], wh[n], acc[m][n], 0, 0, 0);
        acc[m][n] = __builtin_amdgcn_mfma_f32_16x16x32_f16(ah[m], wl[n], acc[m][n], 0, 0, 0);
      }
    __syncthreads();
  }
  float* Sf = (float*)S;
  const int LS = 132;
  int erow = tid >> 3;
  int ecol = (tid & 7) * 16;
  #pragma unroll
  for (int m = 0; m < 4; ++m) {
    int lr0 = wr*16 + kg*4;
    #pragma unroll
    for (int n = 0; n < 4; ++n) {
      int lcol = wc*64 + n*16 + lr;
      Sf[(lr0+0)*LS + lcol] = acc[m][n][0];
      Sf[(lr0+1)*LS + lcol] = acc[m][n][1];
      Sf[(lr0+2)*LS + lcol] = acc[m][n][2];
      Sf[(lr0+3)*LS + lcol] = acc[m][n][3];
    }
    __syncthreads();
    int grow = t0 + (erow >> 4)*64 + m*16 + (erow & 15);
    size_t off = ((size_t)b*T_ + grow)*256 + n0 + ecol;
    float f[16];
    #pragma unroll
    for (int j = 0; j < 16; ++j) f[j] = Sf[erow*LS + ecol + j];
    #pragma unroll
    for (int j = 0; j < 16; ++j) {
      float v = f[j];
      if (bias) v += bias[n0 + ecol + j];
      if (ACT == 1) v = fmaxf(v, 0.f);
      if (ACT == 2) v = 1.f/(1.f + __expf(-v));
      if (ACT == 3) v = 0.5f*v*(1.f + erff(v*0.7071067811865475f));
      f[j] = v;
    }
    if (Rh) {
      half8 rh0 = *(const half8*)(Rh + off), rh1 = *(const half8*)(Rh + off + 8);
      half8 rl0 = *(const half8*)(Rl + off), rl1 = *(const half8*)(Rl + off + 8);
      #pragma unroll
      for (int j = 0; j < 8; ++j) { f[j] += join2(rh0[j], rl0[j]); f[j+8] += join2(rh1[j], rl1[j]); }
    }
    if (SGL) {
      half8 o0, o1;
      #pragma unroll
      for (int j = 0; j < 8; ++j) { o0[j] = (h16)f[j]; o1[j] = (h16)f[j+8]; }
      *(half8*)(Ch + off) = o0; *(half8*)(Ch + off + 8) = o1;
    } else {
      half8 oh0, ol0, oh1, ol1;
      #pragma unroll
      for (int j = 0; j < 8; ++j) {
        h16 hh = (h16)f[j];   oh0[j] = hh; ol0[j] = (h16)(f[j]   - (float)hh);
        h16 h2 = (h16)f[j+8]; oh1[j] = h2; ol1[j] = (h16)(f[j+8] - (float)h2);
      }
      *(half8*)(Ch + off) = oh0; *(half8*)(Ch + off + 8) = oh1;
      *(half8*)(Cl + off) = ol0; *(half8*)(Cl + off + 8) = ol1;
    }
    __syncthreads();
  }
}

// ============================================================================
// Standalone GEMM: A hi/lo, W hi only. BK=64: 12 chunks (48KB LDS), 4 MFMA
// per (m,n) per barrier -> K=256 in 4 barrier pairs. For SFI ff1/ff2.
// ============================================================================
template<int ACT>
__global__ __launch_bounds__(256, 2) void gemm_p_wh(
    const h16* __restrict__ Agh, const h16* __restrict__ Agl,
    const h16* __restrict__ Wg,
    const float* __restrict__ bias,
    const h16* __restrict__ Rh, const h16* __restrict__ Rl,
    h16* __restrict__ Ch, h16* __restrict__ Cl,
    size_t wbs)
{
  int b  = blockIdx.z;
  int n0 = blockIdx.x * 128;
  int t0 = blockIdx.y * 128;
  const h16* Ah_g = Agh + (size_t)b*T_*256;
  const h16* Al_g = Agl + (size_t)b*T_*256;
  const h16* W_g  = Wg + (size_t)b*wbs;
  __shared__ h16 S[24576];
  int tid = threadIdx.x, l = tid & 63, wid = tid >> 6;
  int wr = wid >> 1, wc = wid & 1, lr = l & 15, kg = l >> 4;
  f32x4 acc[4][4];
  #pragma unroll
  for (int m = 0; m < 4; ++m)
    #pragma unroll
    for (int n = 0; n < 4; ++n) acc[m][n] = (f32x4){0.f,0.f,0.f,0.f};

  for (int k0 = 0; k0 < 256; k0 += 64) {
    #pragma unroll
    for (int i = 0; i < 12; ++i) {
      int c = i*256 + tid;        // 0..3071
      int p = c >> 9, r = (c >> 2) & 127, kc = c & 3;
      int ks = k0 + (p & 1)*32 + ((kc ^ ((r >> 1) & 3)) << 3);
      const h16* src = (p < 2) ? Ah_g + (size_t)(t0 + r)*256 + ks
                     : (p < 4) ? Al_g + (size_t)(t0 + r)*256 + ks
                               : W_g  + (size_t)(n0 + r)*256 + ks;
      gl2lds16(src, S + (size_t)c*8);
    }
    __syncthreads();
    half8 a0[4], a1[4], l0[4], l1[4], w0[4], w1[4];
    #pragma unroll
    for (int m = 0; m < 4; ++m) {
      int row = wr*64 + m*16 + lr;
      int ko = (kg ^ ((row >> 1) & 3)) * 8;
      a0[m] = *(const half8*)&S[row*32 + ko];
      a1[m] = *(const half8*)&S[4096 + row*32 + ko];
      l0[m] = *(const half8*)&S[8192 + row*32 + ko];
      l1[m] = *(const half8*)&S[12288 + row*32 + ko];
    }
    #pragma unroll
    for (int n = 0; n < 4; ++n) {
      int row = wc*64 + n*16 + lr;
      int ko = (kg ^ ((row >> 1) & 3)) * 8;
      w0[n] = *(const half8*)&S[16384 + row*32 + ko];
      w1[n] = *(const half8*)&S[20480 + row*32 + ko];
    }
    #pragma unroll
    for (int m = 0; m < 4; ++m)
      #pragma unroll
      for (int n = 0; n < 4; ++n) {
        acc[m][n] = __builtin_amdgcn_mfma_f32_16x16x32_f16(a0[m], w0[n], acc[m][n], 0, 0, 0);
        acc[m][n] = __builtin_amdgcn_mfma_f32_16x16x32_f16(l0[m], w0[n], acc[m][n], 0, 0, 0);
        acc[m][n] = __builtin_amdgcn_mfma_f32_16x16x32_f16(a1[m], w1[n], acc[m][n], 0, 0, 0);
        acc[m][n] = __builtin_amdgcn_mfma_f32_16x16x32_f16(l1[m], w1[n], acc[m][n], 0, 0, 0);
      }
    __syncthreads();
  }
  float* Sf = (float*)S;
  const int LS = 132;
  int erow = tid >> 3;
  int ecol = (tid & 7) * 16;
  #pragma unroll
  for (int m = 0; m < 4; ++m) {
    int lr0 = wr*16 + kg*4;
    #pragma unroll
    for (int n = 0; n < 4; ++n) {
      int lcol = wc*64 + n*16 + lr;
      Sf[(lr0+0)*LS + lcol] = acc[m][n][0];
      Sf[(lr0+1)*LS + lcol] = acc[m][n][1];
      Sf[(lr0+2)*LS + lcol] = acc[m][n][2];
      Sf[(lr0+3)*LS + lcol] = acc[m][n][3];
    }
    __syncthreads();
    int grow = t0 + (erow >> 4)*64 + m*16 + (erow & 15);
    size_t off = ((size_t)b*T_ + grow)*256 + n0 + ecol;
    float f[16];
    #pragma unroll
    for (int j = 0; j < 16; ++j) {
      float v = Sf[erow*LS + ecol + j] + bias[n0 + ecol + j];
      if (ACT == 3) v = 0.5f*v*(1.f + erff(v*0.7071067811865475f));
      f[j] = v;
    }
    if (Rh) {
      half8 rh0 = *(const half8*)(Rh + off), rh1 = *(const half8*)(Rh + off + 8);
      half8 rl0 = *(const half8*)(Rl + off), rl1 = *(const half8*)(Rl + off + 8);
      #pragma unroll
      for (int j = 0; j < 8; ++j) { f[j] += join2(rh0[j], rl0[j]); f[j+8] += join2(rh1[j], rl1[j]); }
    }
    half8 oh0, ol0, oh1, ol1;
    #pragma unroll
    for (int j = 0; j < 8; ++j) {
      h16 hh = (h16)f[j];   oh0[j] = hh; ol0[j] = (h16)(f[j]   - (float)hh);
      h16 h2 = (h16)f[j+8]; oh1[j] = h2; ol1[j] = (h16)(f[j+8] - (float)h2);
    }
    *(half8*)(Ch + off) = oh0; *(half8*)(Ch + off + 8) = oh1;
    *(half8*)(Cl + off) = ol0; *(half8*)(Cl + off + 8) = ol1;
    __syncthreads();
  }
}

// ============================================================================
// Fused attention-out GEMM: out = [att|conv] @ Wcat(hi)^T + bias3 + fst.
// A single fp16 (two sources); W hi only. BK=64 (r21-proven).
// ============================================================================
__global__ __launch_bounds__(256, 2) void gemm_attout(
    const h16* __restrict__ A1f, const h16* __restrict__ A2f,
    const h16* __restrict__ Wg,
    const float* __restrict__ bias,
    const h16* __restrict__ Rh, const h16* __restrict__ Rl,
    h16* __restrict__ Ch, h16* __restrict__ Cl)
{
  int b  = blockIdx.z;
  int n0 = blockIdx.x * 128;
  int t0 = blockIdx.y * 128;
  size_t abase = (size_t)b*T_*256;
  __shared__ h16 S[16384];
  int tid = threadIdx.x, l = tid & 63, wid = tid >> 6;
  int wr = wid >> 1, wc = wid & 1, lr = l & 15, kg = l >> 4;
  f32x4 acc[4][4];
  #pragma unroll
  for (int m = 0; m < 4; ++m)
    #pragma unroll
    for (int n = 0; n < 4; ++n) acc[m][n] = (f32x4){0.f,0.f,0.f,0.f};

  for (int k0 = 0; k0 < 512; k0 += 64) {
    #pragma unroll
    for (int i = 0; i < 8; ++i) {
      int c = i*256 + tid;        // 0..2047
      int p = c >> 9, r = (c >> 2) & 127, kc = c & 3;
      int ks = k0 + (p & 1)*32 + ((kc ^ ((r >> 1) & 3)) << 3);
      const h16* src;
      if (p < 2) {
        if (ks < 256) src = A1f + abase + (size_t)(t0 + r)*256 + ks;
        else          src = A2f + abase + (size_t)(t0 + r)*256 + (ks - 256);
      } else {
        src = Wg + (size_t)(n0 + r)*512 + ks;
      }
      gl2lds16(src, S + (size_t)c*8);
    }
    __syncthreads();
    half8 a0[4], a1[4], w0[4], w1[4];
    #pragma unroll
    for (int m = 0; m < 4; ++m) {
      int row = wr*64 + m*16 + lr;
      int ko = (kg ^ ((row >> 1) & 3)) * 8;
      a0[m] = *(const half8*)&S[row*32 + ko];
      a1[m] = *(const half8*)&S[4096 + row*32 + ko];
    }
    #pragma unroll
    for (int n = 0; n < 4; ++n) {
      int row = wc*64 + n*16 + lr;
      int ko = (kg ^ ((row >> 1) & 3)) * 8;
      w0[n] = *(const half8*)&S[8192 + row*32 + ko];
      w1[n] = *(const half8*)&S[12288 + row*32 + ko];
    }
    #pragma unroll
    for (int m = 0; m < 4; ++m)
      #pragma unroll
      for (int n = 0; n < 4; ++n) {
        acc[m][n] = __builtin_amdgcn_mfma_f32_16x16x32_f16(a0[m], w0[n], acc[m][n], 0, 0, 0);
        acc[m][n] = __builtin_amdgcn_mfma_f32_16x16x32_f16(a1[m], w1[n], acc[m][n], 0, 0, 0);
      }
    __syncthreads();
  }
  float* Sf = (float*)S;
  const int LS = 132;
  int erow = tid >> 3;
  int ecol = (tid & 7) * 16;
  #pragma unroll
  for (int m = 0; m < 4; ++m) {
    int lr0 = wr*16 + kg*4;
    #pragma unroll
    for (int n = 0; n < 4; ++n) {
      int lcol = wc*64 + n*16 + lr;
      Sf[(lr0+0)*LS + lcol] = acc[m][n][0];
      Sf[(lr0+1)*LS + lcol] = acc[m][n][1];
      Sf[(lr0+2)*LS + lcol] = acc[m][n][2];
      Sf[(lr0+3)*LS + lcol] = acc[m][n][3];
    }
    __syncthreads();
    int grow = t0 + (erow >> 4)*64 + m*16 + (erow & 15);
    size_t off = ((size_t)b*T_ + grow)*256 + n0 + ecol;
    float f[16];
    #pragma unroll
    for (int j = 0; j < 16; ++j) f[j] = Sf[erow*LS + ecol + j] + bias[n0 + ecol + j];
    half8 rh0 = *(const half8*)(Rh + off), rh1 = *(const half8*)(Rh + off + 8);
    half8 rl0 = *(const half8*)(Rl + off), rl1 = *(const half8*)(Rl + off + 8);
    #pragma unroll
    for (int j = 0; j < 8; ++j) { f[j] += join2(rh0[j], rl0[j]); f[j+8] += join2(rh1[j], rl1[j]); }
    half8 oh0, ol0, oh1, ol1;
    #pragma unroll
    for (int j = 0; j < 8; ++j) {
      h16 hh = (h16)f[j];   oh0[j] = hh; ol0[j] = (h16)(f[j]   - (float)hh);
      h16 h2 = (h16)f[j+8]; oh1[j] = h2; ol1[j] = (h16)(f[j+8] - (float)h2);
    }
    *(half8*)(Ch + off) = oh0; *(half8*)(Ch + off + 8) = oh1;
    *(half8*)(Cl + off) = ol0; *(half8*)(Cl + off + 8) = ol1;
    __syncthreads();
  }
}

// ============================================================================
// Merged K/V/Q projection: A single, W' hi only. BK=64 (r21-proven).
// XCD-swizzled flat grid 1536, 2 blocks/CU.
// ============================================================================
__global__ __launch_bounds__(256, 2) void gemm_qkv(
    const h16* __restrict__ Af, const h16* __restrict__ Wqkv,
    const float* __restrict__ bias2,
    h16* __restrict__ Kf, h16* __restrict__ Vf, h16* __restrict__ Qf)
{
  int fid = blockIdx.x;
  int swz = (fid & 7)*192 + (fid >> 3);
  int xsel = swz % 6;
  int sel = xsel >> 1;
  int n0  = (xsel & 1) * 128;
  int t0  = ((swz / 6) & 63) * 128;
  int b   = swz / 384;
  const h16* A_g = Af + (size_t)b*T_*256;
  const h16* W_g = Wqkv + (size_t)(sel*4 + b)*65536;
  const float* bias = bias2 + (size_t)(sel*4 + b)*256;
  h16* dst = sel == 0 ? Kf : sel == 1 ? Vf : Qf;
  __shared__ h16 S[16384];
  int tid = threadIdx.x, l = tid & 63, wid = tid >> 6;
  int wr = wid >> 1, wc = wid & 1, lr = l & 15, kg = l >> 4;
  f32x4 acc[4][4];
  #pragma unroll
  for (int m = 0; m < 4; ++m)
    #pragma unroll
    for (int n = 0; n < 4; ++n) acc[m][n] = (f32x4){0.f,0.f,0.f,0.f};

  for (int k0 = 0; k0 < 256; k0 += 64) {
    #pragma unroll
    for (int i = 0; i < 8; ++i) {
      int c = i*256 + tid;        // 0..2047
      int p = c >> 9, r = (c >> 2) & 127, kc = c & 3;
      int ks = k0 + (p & 1)*32 + ((kc ^ ((r >> 1) & 3)) << 3);
      const h16* src = (p < 2) ? A_g + (size_t)(t0 + r)*256 + ks
                               : W_g + (size_t)(n0 + r)*256 + ks;
      gl2lds16(src, S + (size_t)c*8);
    }
    __syncthreads();
    half8 a0[4], a1[4], w0[4], w1[4];
    #pragma unroll
    for (int m = 0; m < 4; ++m) {
      int row = wr*64 + m*16 + lr;
      int ko = (kg ^ ((row >> 1) & 3)) * 8;
      a0[m] = *(const half8*)&S[row*32 + ko];
      a1[m] = *(const half8*)&S[4096 + row*32 + ko];
    }
    #pragma unroll
    for (int n = 0; n < 4; ++n) {
      int row = wc*64 + n*16 + lr;
      int ko = (kg ^ ((row >> 1) & 3)) * 8;
      w0[n] = *(const half8*)&S[8192 + row*32 + ko];
      w1[n] = *(const half8*)&S[12288 + row*32 + ko];
    }
    #pragma unroll
    for (int m = 0; m < 4; ++m)
      #pragma unroll
      for (int n = 0; n < 4; ++n) {
        acc[m][n] = __builtin_amdgcn_mfma_f32_16x16x32_f16(a0[m], w0[n], acc[m][n], 0, 0, 0);
        acc[m][n] = __builtin_amdgcn_mfma_f32_16x16x32_f16(a1[m], w1[n], acc[m][n], 0, 0, 0);
      }
    __syncthreads();
  }
  float* Sf = (float*)S;
  const int LS = 132;
  int erow = tid >> 3;
  int ecol = (tid & 7) * 16;
  #pragma unroll
  for (int m = 0; m < 4; ++m) {
    int lr0 = wr*16 + kg*4;
    #pragma unroll
    for (int n = 0; n < 4; ++n) {
      int lcol = wc*64 + n*16 + lr;
      Sf[(lr0+0)*LS + lcol] = acc[m][n][0];
      Sf[(lr0+1)*LS + lcol] = acc[m][n][1];
      Sf[(lr0+2)*LS + lcol] = acc[m][n][2];
      Sf[(lr0+3)*LS + lcol] = acc[m][n][3];
    }
    __syncthreads();
    int grow = t0 + (erow >> 4)*64 + m*16 + (erow & 15);
    size_t off = ((size_t)b*T_ + grow)*256 + n0 + ecol;
    half8 o0, o1;
    #pragma unroll
    for (int j = 0; j < 8; ++j) {
      float v0 = Sf[erow*LS + ecol + j]     + bias[n0 + ecol + j];
      float v1 = Sf[erow*LS + ecol + 8 + j] + bias[n0 + ecol + 8 + j];
      if (sel != 1) {
        v0 = 1.f/(1.f + __expf(-v0));
        v1 = 1.f/(1.f + __expf(-v1));
      }
      o0[j] = (h16)v0; o1[j] = (h16)v1;
    }
    *(half8*)(dst + off) = o0; *(half8*)(dst + off + 8) = o1;
    __syncthreads();
  }
}

// ============================================================================
// Dilated conv: 3-tap MFMA GEMM + fused stats. A hi only, W hi only.
// BK=64 (r21-proven). Output single fp16. XCD-swizzled flat grid 512.
// ============================================================================
__global__ __launch_bounds__(256, 2) void conv_p(
    const h16* __restrict__ Agh,
    const h16* __restrict__ Wg,
    const float* __restrict__ bias,
    h16* __restrict__ Cf,
    float* __restrict__ stats, const float* __restrict__ zbuf, int dil)
{
  int fid = blockIdx.x;
  int swz = (fid & 7)*64 + (fid >> 3);
  int n0 = (swz & 1) * 128;
  int t0 = ((swz >> 1) & 63) * 128;
  int b  = swz >> 7;
  const h16* Ah_g = Agh + (size_t)b*T_*256;
  __shared__ h16 S[16384];
  __shared__ float cstat[2][128];
  int tid = threadIdx.x, l = tid & 63, wid = tid >> 6;
  int wr = wid >> 1, wc = wid & 1, lr = l & 15, kg = l >> 4;
  f32x4 acc[4][4];
  #pragma unroll
  for (int m = 0; m < 4; ++m)
    #pragma unroll
    for (int n = 0; n < 4; ++n) acc[m][n] = (f32x4){0.f,0.f,0.f,0.f};

  for (int tap = 0; tap < 3; ++tap) {
    int off = (tap - 1) * dil;
    const h16* W_t = Wg + (size_t)tap*65536;
    for (int k0 = 0; k0 < 256; k0 += 64) {
      #pragma unroll
      for (int i = 0; i < 8; ++i) {
        int c = i*256 + tid;        // 0..2047
        int p = c >> 9, r = (c >> 2) & 127, kc = c & 3;
        int ks = k0 + (p & 1)*32 + ((kc ^ ((r >> 1) & 3)) << 3);
        const h16* src;
        if (p < 2) {
          int rt = t0 + r + off;
          if ((unsigned)rt < (unsigned)T_)
            src = Ah_g + (size_t)rt*256 + ks;
          else
            src = (const h16*)zbuf;
        } else {
          src = W_t + (size_t)(n0 + r)*256 + ks;
        }
        gl2lds16(src, S + (size_t)c*8);
      }
      __syncthreads();
      half8 a0[4], a1[4], w0[4], w1[4];
      #pragma unroll
      for (int m = 0; m < 4; ++m) {
        int row = wr*64 + m*16 + lr;
        int ko = (kg ^ ((row >> 1) & 3)) * 8;
        a0[m] = *(const half8*)&S[row*32 + ko];
        a1[m] = *(const half8*)&S[4096 + row*32 + ko];
      }
      #pragma unroll
      for (int n = 0; n < 4; ++n) {
        int row = wc*64 + n*16 + lr;
        int ko = (kg ^ ((row >> 1) & 3)) * 8;
        w0[n] = *(const half8*)&S[8192 + row*32 + ko];
        w1[n] = *(const half8*)&S[12288 + row*32 + ko];
      }
      #pragma unroll
      for (int m = 0; m < 4; ++m)
        #pragma unroll
        for (int n = 0; n < 4; ++n) {
          acc[m][n] = __builtin_amdgcn_mfma_f32_16x16x32_f16(a0[m], w0[n], acc[m][n], 0, 0, 0);
          acc[m][n] = __builtin_amdgcn_mfma_f32_16x16x32_f16(a1[m], w1[n], acc[m][n], 0, 0, 0);
        }
      __syncthreads();
    }
  }
  cstat[tid >> 7][tid & 127] = 0.f;
  __syncthreads();
  #pragma unroll
  for (int n = 0; n < 4; ++n) {
    int cl = wc*64 + n*16 + lr;
    float bi = bias[n0 + cl];
    float s = 0.f, s2 = 0.f;
    #pragma unroll
    for (int m = 0; m < 4; ++m)
      #pragma unroll
      for (int r = 0; r < 4; ++r) {
        float v = fmaxf(acc[m][n][r] + bi, 0.f);
        acc[m][n][r] = v;
        s += v; s2 += v*v;
      }
    atomicAdd(&cstat[0][cl], s);
    atomicAdd(&cstat[1][cl], s2);
  }
  __syncthreads();
  if (tid < 128)      atomicAdd(&stats[b*512 + n0 + tid], cstat[0][tid]);
  else if (tid < 256) atomicAdd(&stats[b*512 + 256 + n0 + (tid-128)], cstat[1][tid-128]);
  __syncthreads();
  float* Sf = (float*)S;
  const int LS = 132;
  int erow = tid >> 3;
  int ecol = (tid & 7) * 16;
  #pragma unroll
  for (int m = 0; m < 4; ++m) {
    int lr0 = wr*16 + kg*4;
    #pragma unroll
    for (int n = 0; n < 4; ++n) {
      int lcol = wc*64 + n*16 + lr;
      Sf[(lr0+0)*LS + lcol] = acc[m][n][0];
      Sf[(lr0+1)*LS + lcol] = acc[m][n][1];
      Sf[(lr0+2)*LS + lcol] = acc[m][n][2];
      Sf[(lr0+3)*LS + lcol] = acc[m][n][3];
    }
    __syncthreads();
    int grow = t0 + (erow >> 4)*64 + m*16 + (erow & 15);
    size_t off2 = ((size_t)b*T_ + grow)*256 + n0 + ecol;
    half8 o0, o1;
    #pragma unroll
    for (int j = 0; j < 8; ++j) {
      o0[j] = (h16)Sf[erow*LS + ecol + j];
      o1[j] = (h16)Sf[erow*LS + ecol + 8 + j];
    }
    *(half8*)(Cf + off2) = o0; *(half8*)(Cf + off2 + 8) = o1;
    __syncthreads();
  }
}

// ============================================================================
// kv partial via MFMA (gram-style transposed staging): KV[d][e] =
// sum_t K[t][d] V[t][e], plus ksum[d]. grid (16,16), K=512 per block.
// ============================================================================
__global__ __launch_bounds__(256) void kv_part_p(
    const h16* __restrict__ Kf, const h16* __restrict__ Vf,
    float* __restrict__ pkv)
{
  int bh = blockIdx.y, b = bh >> 2, h = bh & 3;
  int t0 = blockIdx.x * 512;
  __shared__ h16 S[2][64][64];
  __shared__ float ksum[64];
  int tid = threadIdx.x, l = tid & 63, wid = tid >> 6;
  int lr = l & 15, kg = l >> 4;
  if (tid < 64) ksum[tid] = 0.f;
  float ksp[8] = {};
  f32x4 acc[4];
  #pragma unroll
  for (int n = 0; n < 4; ++n) acc[n] = (f32x4){0.f,0.f,0.f,0.f};

  for (int k0 = 0; k0 < 512; k0 += 64) {
    __syncthreads();
    #pragma unroll
    for (int i = 0; i < 2; ++i) {
      int q = tid + i*256;          // 0..511
      int tt = q >> 3;              // 0..63
      int c8 = (q & 7) * 8;         // 0..56
      size_t row = ((size_t)b*T_ + t0 + k0 + tt)*256 + h*64;
      half8 k8 = *(const half8*)(Kf + row + c8);
      half8 v8 = *(const half8*)(Vf + row + c8);
      int ts = tt ^ ((q & 3) << 3);
      #pragma unroll
      for (int j = 0; j < 8; ++j) {
        S[0][c8+j][ts] = k8[j];
        S[1][c8+j][ts] = v8[j];
        ksp[j] += (float)k8[j];
      }
    }
    __syncthreads();
    half8 a0, a1, b0[4], b1[4];
    {
      int row = wid*16 + lr;
      int ko = (kg*8) ^ (((row >> 3) & 3) << 3);
      a0 = *(const half8*)&S[0][row][ko];
      a1 = *(const half8*)&S[0][row][32 + ko];
    }
    #pragma unroll
    for (int n = 0; n < 4; ++n) {
      int row = n*16 + lr;
      int ko = (kg*8) ^ (((row >> 3) & 3) << 3);
      b0[n] = *(const half8*)&S[1][row][ko];
      b1[n] = *(const half8*)&S[1][row][32 + ko];
    }
    #pragma unroll
    for (int n = 0; n < 4; ++n) {
      acc[n] = __builtin_amdgcn_mfma_f32_16x16x32_f16(a0, b0[n], acc[n], 0, 0, 0);
      acc[n] = __builtin_amdgcn_mfma_f32_16x16x32_f16(a1, b1[n], acc[n], 0, 0, 0);
    }
  }
  __syncthreads();
  {
    int dbase = (tid & 7) * 8;
    #pragma unroll
    for (int j = 0; j < 8; ++j) atomicAdd(&ksum[dbase + j], ksp[j]);
  }
  __syncthreads();
  float* dst = pkv + ((size_t)blockIdx.x*16 + bh)*4160;
  #pragma unroll
  for (int n = 0; n < 4; ++n) {
    int e = n*16 + lr;
    #pragma unroll
    for (int r = 0; r < 4; ++r) {
      int d = wid*16 + kg*4 + r;
      dst[d*64 + e] = acc[n][r];
    }
  }
  if (tid < 64) dst[4096 + tid] = ksum[tid];
}

// ============================================================================
// kv final: reduce 16 slabs -> KV^T hi/lo fp16 planes [80][64] per bh.
// Rows 0..63 = KV^T[e][d]; row 64 = ksum[d] + 1e-6; rows 65..79 = 0.
// ============================================================================
__global__ __launch_bounds__(256) void kv_final_k(
    const float* __restrict__ pkv, h16* __restrict__ kvT)
{
  int bh = blockIdx.x;
  for (int idx = threadIdx.x; idx < 5120; idx += 256) {
    int e = idx >> 6, d = idx & 63;
    float s = 0.f;
    if (e < 64) {
      #pragma unroll
      for (int c = 0; c < 16; ++c) s += pkv[((size_t)c*16 + bh)*4160 + d*64 + e];
    } else if (e == 64) {
      #pragma unroll
      for (int c = 0; c < 16; ++c) s += pkv[((size_t)c*16 + bh)*4160 + 4096 + d];
      s += 1e-6f;
    }
    split2(s, &kvT[(size_t)bh*10240 + idx], &kvT[(size_t)bh*10240 + 5120 + idx]);
  }
}

// ============================================================================
// att apply via MFMA: O[t][e] = (Q[t][:] @ KV[:][e]) / (Q[t][:] @ ks).
// Q single fp16 in, O single fp16 out (aliases Q). Tile 128 rows x 64+16 cols,
// single-shot staging (Q 16KB + KV^T hi/lo 20KB), 4 waves x 40 MFMA.
// ============================================================================
__global__ __launch_bounds__(256) void att_apply_p(
    const h16* __restrict__ Qf, const h16* __restrict__ kvT,
    h16* __restrict__ Of)
{
  int bh = blockIdx.y, b = bh >> 2, h = bh & 3;
  int t0 = blockIdx.x * 128;
  __shared__ h16 S[18432];      // Q[128][64] + kvT_h[80][64] + kvT_l[80][64]
  int tid = threadIdx.x, l = tid & 63, wid = tid >> 6;
  int lr = l & 15, kg = l >> 4;

  // stage Q rows t0..t0+127 (layout [r][64], swizzled per 32-half)
  #pragma unroll
  for (int i = 0; i < 4; ++i) {
    int c = i*256 + tid;              // 0..1023
    int r = c >> 3, k8 = c & 7;
    int half = k8 >> 2, kq = k8 & 3;
    int kk = (kq ^ ((r >> 1) & 3)) * 8;
    gl2lds16(Qf + ((size_t)b*T_ + t0 + r)*256 + h*64 + half*32 + kk,
             S + (size_t)c*8);
  }
  // stage kvT hi (rows 0..79) then lo, same layout
  const h16* kvb = kvT + (size_t)bh*10240;
  #pragma unroll
  for (int i = 0; i < 5; ++i) {
    int c = i*256 + tid;              // 0..1279
    int p = (c >= 640) ? 1 : 0;
    int cc = c - p*640;
    int r = cc >> 3, k8 = cc & 7;
    int half = k8 >> 2, kq = k8 & 3;
    int kk = (kq ^ ((r >> 1) & 3)) * 8;
    gl2lds16(kvb + p*5120 + r*64 + half*32 + kk,
             S + 8192 + (size_t)c*8);
  }
  __syncthreads();

  f32x4 acc[2][5];
  #pragma unroll
  for (int m = 0; m < 2; ++m)
    #pragma unroll
    for (int n = 0; n < 5; ++n) acc[m][n] = (f32x4){0.f,0.f,0.f,0.f};

  half8 a0[2], a1[2];
  #pragma unroll
  for (int m = 0; m < 2; ++m) {
    int row = wid*32 + m*16 + lr;
    int ko = (kg ^ ((row >> 1) & 3)) * 8;
    a0[m] = *(const half8*)&S[row*64 + ko];
    a1[m] = *(const half8*)&S[row*64 + 32 + ko];
  }
  #pragma unroll
  for (int n = 0; n < 5; ++n) {
    int roww = n*16 + lr;
    int ko = (kg ^ ((roww >> 1) & 3)) * 8;
    half8 wh0 = *(const half8*)&S[8192 + roww*64 + ko];
    half8 wh1 = *(const half8*)&S[8192 + roww*64 + 32 + ko];
    half8 wl0 = *(const half8*)&S[13312 + roww*64 + ko];
    half8 wl1 = *(const half8*)&S[13312 + roww*64 + 32 + ko];
    #pragma unroll
    for (int m = 0; m < 2; ++m) {
      acc[m][n] = __builtin_amdgcn_mfma_f32_16x16x32_f16(a0[m], wh0, acc[m][n], 0, 0, 0);
      acc[m][n] = __builtin_amdgcn_mfma_f32_16x16x32_f16(a0[m], wl0, acc[m][n], 0, 0, 0);
      acc[m][n] = __builtin_amdgcn_mfma_f32_16x16x32_f16(a1[m], wh1, acc[m][n], 0, 0, 0);
      acc[m][n] = __builtin_amdgcn_mfma_f32_16x16x32_f16(a1[m], wl1, acc[m][n], 0, 0, 0);
    }
  }

  // den lives in col 0 of n-tile 4 (lanes with lr==0); broadcast + scale + store
  #pragma unroll
  for (int m = 0; m < 2; ++m) {
    float z[4];
    #pragma unroll
    for (int r = 0; r < 4; ++r) {
      float dv = __shfl(acc[m][4][r], (l >> 4) << 4);
      z[r] = 1.f / dv;
    }
    #pragma unroll
    for (int r = 0; r < 4; ++r) {
      int grow = t0 + wid*32 + m*16 + kg*4 + r;
      size_t base = ((size_t)b*T_ + grow)*256 + h*64;
      #pragma unroll
      for (int n = 0; n < 4; ++n)
        Of[base + n*16 + lr] = (h16)(acc[m][n][r] * z[r]);
    }
  }
}

// ============================================================================
// SFI gram partial: A (fsc single) x B (fst hi). BK=64 transposed staging,
// 2 MFMA per (m,n) per barrier -> 4 barrier pairs. grid (32,4,B).
// ============================================================================
__global__ __launch_bounds__(256, 2) void gram_part_p(
    const h16* __restrict__ Af, const h16* __restrict__ Bf,
    float* __restrict__ pg)
{
  int b = blockIdx.z;
  int quad = blockIdx.y;
  int slab = blockIdx.x;
  int c0 = (quad >> 1) * 128, d0 = (quad & 1) * 128;
  int t0 = slab * 256;
  __shared__ h16 S[2][128][64];
  int tid = threadIdx.x, l = tid & 63, wid = tid >> 6;
  int wr = wid >> 1, wc = wid & 1, lr = l & 15, kg = l >> 4;
  f32x4 acc[4][4];
  #pragma unroll
  for (int m = 0; m < 4; ++m)
    #pragma unroll
    for (int n = 0; n < 4; ++n) acc[m][n] = (f32x4){0.f,0.f,0.f,0.f};

  for (int k0 = 0; k0 < 256; k0 += 64) {
    #pragma unroll
    for (int i = 0; i < 4; ++i) {
      int q = tid + i*256;        // 0..1023
      int tt = q >> 4;            // 0..63
      int c8 = (q & 15) * 8;
      size_t row = ((size_t)b*T_ + t0 + k0 + tt) * 256;
      half8 a8 = *(const half8*)(Af + row + c0 + c8);
      half8 b8 = *(const half8*)(Bf + row + d0 + c8);
      int ts = tt ^ ((q & 3) << 3);
      #pragma unroll
      for (int j = 0; j < 8; ++j) {
        S[0][c8+j][ts] = a8[j];
        S[1][c8+j][ts] = b8[j];
      }
    }
    __syncthreads();
    half8 a0[4], a1[4], b0[4], b1[4];
    #pragma unroll
    for (int m = 0; m < 4; ++m) {
      int row = wr*64 + m*16 + lr;
      int ko = (kg*8) ^ (((row >> 3) & 3) << 3);
      a0[m] = *(const half8*)&S[0][row][ko];
      a1[m] = *(const half8*)&S[0][row][32 + ko];
    }
    #pragma unroll
    for (int n = 0; n < 4; ++n) {
      int row = wc*64 + n*16 + lr;
      int ko = (kg*8) ^ (((row >> 3) & 3) << 3);
      b0[n] = *(const half8*)&S[1][row][ko];
      b1[n] = *(const half8*)&S[1][row][32 + ko];
    }
    #pragma unroll
    for (int m = 0; m < 4; ++m)
      #pragma unroll
      for (int n = 0; n < 4; ++n) {
        acc[m][n] = __builtin_amdgcn_mfma_f32_16x16x32_f16(a0[m], b0[n], acc[m][n], 0, 0, 0);
        acc[m][n] = __builtin_amdgcn_mfma_f32_16x16x32_f16(a1[m], b1[n], acc[m][n], 0, 0, 0);
      }
    __syncthreads();
  }
  float* dst = pg + ((size_t)(slab*B_ + b)*4 + quad)*16384;
  #pragma unroll
  for (int m = 0; m < 4; ++m)
    #pragma unroll
    for (int n = 0; n < 4; ++n) {
      int cl = wr*64 + m*16 + kg*4;
      int dl = wc*64 + n*16 + lr;
      #pragma unroll
      for (int r = 0; r < 4; ++r)
        dst[(size_t)(cl + r)*128 + dl] = acc[m][n][r];
    }
}

// reduce 32 slabs + softmax(G/T) per row -> f32 G. grid (B*256), 64 thr.
__global__ __launch_bounds__(64) void gram_smax_p(
    const float* __restrict__ pg, float* __restrict__ G)
{
  int row = blockIdx.x;
  int b = row >> 8, c = row & 255;
  int l = threadIdx.x;
  int d4 = l * 4;
  int quad = ((c >= 128) ? 2 : 0) | ((d4 >= 128) ? 1 : 0);
  size_t base = ((size_t)b*4 + quad)*16384 + (size_t)(c & 127)*128 + (d4 & 127);
  float s0 = 0.f, s1 = 0.f, s2 = 0.f, s3 = 0.f;
  for (int sl = 0; sl < 32; ++sl) {
    const float* p = pg + (size_t)sl*(B_*4*16384) + base;
    float4 v = *(const float4*)p;
    s0 += v.x; s1 += v.y; s2 += v.z; s3 += v.w;
  }
  float v[4] = {s0*(1.f/T_), s1*(1.f/T_), s2*(1.f/T_), s3*(1.f/T_)};
  float mx = fmaxf(fmaxf(v[0], v[1]), fmaxf(v[2], v[3]));
  #pragma unroll
  for (int off = 32; off > 0; off >>= 1) mx = fmaxf(mx, __shfl_xor(mx, off));
  float s = 0.f;
  #pragma unroll
  for (int j = 0; j < 4; ++j) { v[j] = __expf(v[j] - mx); s += v[j]; }
  #pragma unroll
  for (int off = 32; off > 0; off >>= 1) s += __shfl_xor(s, off);
  float inv = 1.f / s;
  float4 o = make_float4(v[0]*inv, v[1]*inv, v[2]*inv, v[3]*inv);
  *(float4*)(G + (size_t)b*65536 + (size_t)c*256 + d4) = o;
}

// ============================================================================
// Final as MFMA GEMM: out[b,o,t] = ((fst . W[o]) + bn[o]) * mask.
// ============================================================================
__global__ __launch_bounds__(256, 2) void gemm_out(
    const h16* __restrict__ Agh, const h16* __restrict__ Agl,
    const h16* __restrict__ Wgh, const h16* __restrict__ Wgl,
    const float* __restrict__ bn, const float* __restrict__ mask,
    float* __restrict__ out)
{
  int bt0 = blockIdx.x * 256;
  int b = bt0 >> 13;
  __shared__ h16 S[20480];
  int tid = threadIdx.x, l = tid & 63, wid = tid >> 6;
  int lr = l & 15, kg = l >> 4;
  f32x4 acc[4][4];
  #pragma unroll
  for (int m = 0; m < 4; ++m)
    #pragma unroll
    for (int n = 0; n < 4; ++n) acc[m][n] = (f32x4){0.f,0.f,0.f,0.f};

  for (int k0 = 0; k0 < 256; k0 += 32) {
    #pragma unroll
    for (int i = 0; i < 10; ++i) {
      int c = i*256 + tid;
      const h16* src;
      if (c < 2048) {
        int p = c >> 10, rem = c & 1023, r = rem >> 2, kc = rem & 3;
        int ks = k0 + ((kc ^ ((r >> 1) & 3)) << 3);
        src = (p ? Agl : Agh) + (size_t)(bt0 + r)*256 + ks;
      } else {
        int c2 = c - 2048;
        int p = c2 >> 8, rem = c2 & 255, r = rem >> 2, kc = rem & 3;
        int ks = k0 + ((kc ^ ((r >> 1) & 3)) << 3);
        src = (p ? Wgl : Wgh) + (size_t)r*256 + ks;
      }
      gl2lds16(src, S + (size_t)c*8);
    }
    __syncthreads();
    half8 ah[4], al[4], wh[4], wl[4];
    #pragma unroll
    for (int m = 0; m < 4; ++m) {
      int row = wid*64 + m*16 + lr;
      int ko = ((kg ^ ((row >> 1) & 3)) << 3);
      ah[m] = *(const half8*)&S[row*32 + ko];
      al[m] = *(const half8*)&S[8192 + row*32 + ko];
    }
    #pragma unroll
    for (int n = 0; n < 4; ++n) {
      int row = n*16 + lr;
      int ko = ((kg ^ ((row >> 1) & 3)) << 3);
      wh[n] = *(const half8*)&S[16384 + row*32 + ko];
      wl[n] = *(const half8*)&S[18432 + row*32 + ko];
    }
    #pragma unroll
    for (int m = 0; m < 4; ++m)
      #pragma unroll
      for (int n = 0; n < 4; ++n) {
        acc[m][n] = __builtin_amdgcn_mfma_f32_16x16x32_f16(ah[m], wh[n], acc[m][n], 0, 0, 0);
        acc[m][n] = __builtin_amdgcn_mfma_f32_16x16x32_f16(al[m], wh[n], acc[m][n], 0, 0, 0);
        acc[m][n] = __builtin_amdgcn_mfma_f32_16x16x32_f16(ah[m], wl[n], acc[m][n], 0, 0, 0);
      }
    __syncthreads();
  }
  #pragma unroll
  for (int m = 0; m < 4; ++m)
    #pragma unroll
    for (int n = 0; n < 4; ++n) {
      int col = n*16 + lr;
      if (col < 48) {
        float bi = bn[col];
        #pragma unroll
        for (int r = 0; r < 4; ++r) {
          int grow = bt0 + wid*64 + m*16 + kg*4 + r;
          int t = grow & (T_ - 1);
          out[((size_t)b*48 + col)*T_ + t] =
              (acc[m][n][r] + bi) * mask[(size_t)b*T_ + t];
        }
      }
    }
}

// ============================================================================
extern "C" void kernel_launch(void* const* d_in, const int* in_sizes, int n_in,
                              void* d_out, int out_size, void* d_ws, size_t ws_size,
                              hipStream_t stream) {
  const float* x         = (const float*)d_in[0];
  const float* mask      = (const float*)d_in[1];
  const float* conv_in_w = (const float*)d_in[2];
  const float* conv_in_b = (const float*)d_in[3];
  const float* conv_t_w  = (const float*)d_in[4];
  const float* conv_t_b  = (const float*)d_in[5];
  const float* sfi_cs_w  = (const float*)d_in[6];
  const float* sfi_cs_b  = (const float*)d_in[7];
  const float* sfi_ff1_w = (const float*)d_in[8];
  const float* sfi_ff1_b = (const float*)d_in[9];
  const float* sfi_ff2_w = (const float*)d_in[10];
  const float* sfi_ff2_b = (const float*)d_in[11];
  const float* ff_w      = (const float*)d_in[12];
  const float* ff_b      = (const float*)d_in[13];
  const float* qw = (const float*)d_in[14]; const float* qb = (const float*)d_in[15];
  const float* kw = (const float*)d_in[16]; const float* kb = (const float*)d_in[17];
  const float* vw = (const float*)d_in[18]; const float* vb = (const float*)d_in[19];
  const float* ow = (const float*)d_in[20]; const float* ob = (const float*)d_in[21];
  const float* co_w = (const float*)d_in[22]; const float* co_b = (const float*)d_in[23];
  const float* out_w = (const float*)d_in[24]; const float* out_b = (const float*)d_in[25];

  float* ws = (float*)d_ws;
  const size_t BT = (size_t)B_ * T_;
  const size_t NB = BT * 256;
  float* smallR = ws;                        // BT*64 f32
  float* bigR   = smallR + BT*64;            // 5 * NB
  float* GR     = bigR + 5*NB;               // B*65536 f32
  float* statsR = GR + (size_t)B_*65536;     // B*512
  float* kvR    = statsR + (size_t)B_*512;   // 16*10240 h16 = 81920 f32
  float* wsfiR  = kvR + 81920;               // 147456
  float* zbufR  = wsfiR + 147456;            // 16 floats

  h16* small_h = (h16*)smallR; h16* small_l = small_h + BT*64;
  h16 *bigH[5], *bigL[5];
  for (int i = 0; i < 5; ++i) { bigH[i] = (h16*)(bigR + (size_t)i*NB); bigL[i] = bigH[i] + NB; }
  float* Gf    = GR;
  float* stats = statsR;
  h16* kvT16   = (h16*)kvR;
  h16* wsfi_h = (h16*)wsfiR; h16* wsfi_l = wsfi_h + 147456;
  float* pkv   = smallR;
  h16* wqkv   = (h16*)smallR;                // 786432 elems (hi only)
  h16* wf_h    = (h16*)smallR;               // 262144 elems (SFI only, hi only)
  h16* wlay   = (h16*)(smallR + 1064960);    // 327680 elems (hi only)
  float* bias2 = smallR + 1392640;           // 3072 f32
  float* bias3 = smallR + 1395712;           // 256 f32

  dim3 gh(2, T_/128, B_);
  dim3 b256(256);

  hipMemsetAsync(zbufR, 0, 64, stream);
  init_fs_k<<<dim3((unsigned)(BT*64/256)), b256, 0, stream>>>(x, conv_in_w, conv_in_b, small_h, small_l, 4);
  wsplit_k<<<dim3(64), b256, 0, stream>>>(conv_t_w, wsfi_h, wsfi_l, 16384);
  gemm_p<0,0><<<gh, b256, 0, stream>>>(small_h, small_l, wsfi_h, wsfi_l, conv_t_b,
                                       nullptr, nullptr, bigH[0], bigL[0], 64, 0);

  int ifst = 0;
  int fr[4] = {1, 2, 3, 4};
  int count = 0;
  for (int i = 0; i < 10; ++i) {
    if (i == 1 || i == 3 || i == 5 || i == 7) {
      // ---- SFI ----
      int a = fr[0], bb = fr[1], c = fr[2], d = fr[3];
      sprep_k<<<dim3(576), b256, 0, stream>>>(sfi_ff1_w + (size_t)count*65536,
                                              sfi_ff2_w + (size_t)count*65536,
                                              sfi_cs_w + (size_t)count*16384,
                                              wsfi_h, wsfi_l);
      init_fs_k<<<dim3((unsigned)(BT*64/256)), b256, 0, stream>>>(x, conv_in_w, conv_in_b, small_h, small_l, count);
      // fsc -> bigH[a] single fp16
      gemm_p<0,1><<<gh, b256, 0, stream>>>(small_h, small_l, wsfi_h + 131072, wsfi_l + 131072,
                                           sfi_cs_b + count*256, nullptr, nullptr,
                                           bigH[a], nullptr, 64, 0);
      float* pgram = bigR + (size_t)bb*NB;
      gram_part_p<<<dim3(32, 4, B_), b256, 0, stream>>>(bigH[a], bigH[ifst], pgram);
      gram_smax_p<<<dim3(B_*256), dim3(64), 0, stream>>>(pgram, Gf);
      mmrow_k<<<dim3(B_*256), b256, 0, stream>>>(sfi_ff1_w + (size_t)count*65536, Gf, wf_h);
      // ff1: W hi-only (wf, per-batch), A = fst hi/lo, gelu
      gemm_p_wh<3><<<gh, b256, 0, stream>>>(bigH[ifst], bigL[ifst], wf_h,
                                            sfi_ff1_b + count*256, nullptr, nullptr,
                                            bigH[c], bigL[c], 65536);
      // ff2: W hi-only (wsfi hi), A hi/lo, + fst residual
      gemm_p_wh<0><<<gh, b256, 0, stream>>>(bigH[c], bigL[c], wsfi_h + 65536,
                                            sfi_ff2_b + count*256, bigH[ifst], bigL[ifst],
                                            bigH[d], bigL[d], 0);
      fr[0] = a; fr[1] = bb; fr[2] = c; fr[3] = ifst;
      ifst = d;
      ++count;
    }
    // ---- attention module ----
    int a = fr[0], bb = fr[1], c = fr[2], d = fr[3];
    int dil = 1 << i;
    prep_layer_k<<<dim3(1289), b256, 0, stream>>>(ff_w + (size_t)i*196608,
                                                  co_w + (size_t)i*65536,
                                                  ow + (size_t)i*65536, ob + i*256,
                                                  co_b + i*256,
                                                  wlay, bias3, stats);
    // conv: A hi only, W hi only -> single fp16
    conv_p<<<dim3(512), b256, 0, stream>>>(bigH[ifst], wlay, ff_b + i*256,
                                           bigH[a], stats, zbufR, dil);
    nwnb_k<<<dim3(3840), b256, 0, stream>>>(qw + (size_t)i*65536, kw + (size_t)i*65536,
                                            vw + (size_t)i*65536,
                                            qb + i*256, kb + i*256, vb + i*256,
                                            stats, wqkv, bias2);
    gemm_qkv<<<dim3(1536), b256, 0, stream>>>(bigH[a], wqkv, bias2,
                                              bigH[bb], bigH[c], bigH[d]);
    kv_part_p<<<dim3(16, 16), b256, 0, stream>>>(bigH[bb], bigH[c], pkv);
    kv_final_k<<<dim3(16), b256, 0, stream>>>(pkv, kvT16);
    att_apply_p<<<dim3(T_/128, 16), b256, 0, stream>>>(bigH[d], kvT16, bigH[d]);
    gemm_attout<<<gh, b256, 0, stream>>>(bigH[d], bigH[a],
                                         wlay + 196608, bias3,
                                         bigH[ifst], bigL[ifst], bigH[bb], bigL[bb]);
    fr[0] = a; fr[1] = c; fr[2] = d; fr[3] = ifst;
    ifst = bb;
  }
  wsplit_out_k<<<dim3(64), b256, 0, stream>>>(out_w, wsfi_h, wsfi_l);
  gemm_out<<<dim3((unsigned)(BT/256)), b256, 0, stream>>>(bigH[ifst], bigL[ifst], wsfi_h, wsfi_l,
                                                          out_b, mask, (float*)d_out);
}

// Round 25
// 1944.555 us; speedup vs baseline: 1.0721x; 1.0721x over previous
//
#include <hip/hip_runtime.h>

#define T_ 8192
#define B_ 4

typedef _Float16 h16;
typedef _Float16 half8 __attribute__((ext_vector_type(8)));
typedef float    f32x4 __attribute__((ext_vector_type(4)));

__device__ __forceinline__ void split2(float v, h16* hp, h16* lp) {
  h16 h = (h16)v; *hp = h; *lp = (h16)(v - (float)h);
}
__device__ __forceinline__ float join2(h16 h, h16 l) {
  return (float)h + (float)l;
}
__device__ __forceinline__ void gl2lds16(const void* g, void* l) {
  __builtin_amdgcn_global_load_lds(
      (const __attribute__((address_space(1))) unsigned int*)g,
      (__attribute__((address_space(3))) unsigned int*)l, 16, 0, 0);
}

// ============================================================================
// init/fs: channel c of input projection -> small planes (B,T,64)
// ============================================================================
__global__ __launch_bounds__(256) void init_fs_k(
    const float* __restrict__ x, const float* __restrict__ cw,
    const float* __restrict__ cb, h16* __restrict__ sh, h16* __restrict__ sl,
    int c)
{
  size_t idx = (size_t)blockIdx.x * 256 + threadIdx.x;   // over B*T*64
  int n = (int)(idx & 63);
  int t = (int)((idx >> 6) & (T_ - 1));
  int b = (int)(idx >> 19);
  float x0 = x[(((size_t)b*3 + 0)*T_ + t)*64 + n];
  float x1 = x[(((size_t)b*3 + 1)*T_ + t)*64 + n];
  float x2 = x[(((size_t)b*3 + 2)*T_ + t)*64 + n];
  float v = cb[c] + x0*cw[c*3] + x1*cw[c*3+1] + x2*cw[c*3+2];
  split2(v, &sh[idx], &sl[idx]);
}

__global__ __launch_bounds__(256) void wsplit_k(
    const float* __restrict__ src, h16* __restrict__ dh, h16* __restrict__ dl,
    int n)
{
  int i = blockIdx.x*256 + threadIdx.x;
  if (i < n) split2(src[i], &dh[i], &dl[i]);
}

// out_w (48x256) -> padded 64x256 planes
__global__ __launch_bounds__(256) void wsplit_out_k(
    const float* __restrict__ src, h16* __restrict__ dh, h16* __restrict__ dl)
{
  int i = blockIdx.x*256 + threadIdx.x;   // 0..16383
  int row = i >> 8;
  float v = (row < 48) ? src[i] : 0.f;
  split2(v, &dh[i], &dl[i]);
}

// ============================================================================
// Per-layer prep (hi-only weights): conv W transpose, W2 = co_w@ow into Wcat
// left half, Wco right half, bias3, stats zero. grid 1289.
// ============================================================================
__global__ __launch_bounds__(256) void prep_layer_k(
    const float* __restrict__ ffw, const float* __restrict__ cow,
    const float* __restrict__ ow, const float* __restrict__ ob,
    const float* __restrict__ cob,
    h16* __restrict__ dh,
    float* __restrict__ bias3, float* __restrict__ stats)
{
  int blk = blockIdx.x, tid = threadIdx.x;
  if (blk < 1024) {
    int i = blk*256 + tid;     // 0..262143
    if (i < 196608) {
      int tap = i >> 16, nk = i & 65535;
      dh[i] = (h16)ffw[(size_t)nk*3 + tap];
    } else {
      int e = i - 196608;
      int n = e >> 8, k = e & 255;
      dh[196608 + n*512 + 256 + k] = (h16)cow[e];
    }
  } else if (blk < 1280) {
    int n = blk - 1024;
    __shared__ float Ar[256];
    int k = tid;
    Ar[k] = cow[n*256 + k];
    __syncthreads();
    float acc = 0.f;
    #pragma unroll 4
    for (int j = 0; j < 256; ++j) acc = fmaf(Ar[j], ow[j*256 + k], acc);
    dh[196608 + n*512 + k] = (h16)acc;
  } else if (blk == 1280) {
    int n = tid;
    float s = cob[n];
    #pragma unroll 4
    for (int j = 0; j < 256; ++j) s = fmaf(cow[n*256 + j], ob[j], s);
    bias3[n] = s;
  } else {
    stats[(blk - 1281)*256 + tid] = 0.f;
  }
}

// per-SFI weight prep: ff1(65536) + ff2(65536) + cs(16384)  (hi/lo)
__global__ __launch_bounds__(256) void sprep_k(
    const float* __restrict__ f1, const float* __restrict__ f2,
    const float* __restrict__ cs, h16* __restrict__ dh, h16* __restrict__ dl)
{
  int i = blockIdx.x*256 + threadIdx.x;   // 0..147455
  float v = (i < 65536) ? f1[i] : (i < 131072) ? f2[i-65536] : cs[i-131072];
  split2(v, &dh[i], &dl[i]);
}

// ============================================================================
// Fused norm-folded QKV weight (hi only) + bias prep. grid 3840.
// ============================================================================
__global__ __launch_bounds__(256) void nwnb_k(
    const float* __restrict__ qw, const float* __restrict__ kw,
    const float* __restrict__ vw,
    const float* __restrict__ qb, const float* __restrict__ kb,
    const float* __restrict__ vb,
    const float* __restrict__ stats,
    h16* __restrict__ dh, float* __restrict__ bias2)
{
  int blk = blockIdx.x, tid = threadIdx.x;
  if (blk < 3072) {
    int i = blk*256 + tid;     // 0..786431
    int k = i & 255;
    int b = (i >> 16) & 3;
    int sel = i >> 18;
    float sm = stats[b*512 + k] * (1.f/T_);
    float s2 = stats[b*512 + 256 + k] * (1.f/T_);
    float iv = rsqrtf(fmaxf(s2 - sm*sm, 0.f) + 1e-5f);
    const float* w = sel == 0 ? kw : sel == 1 ? vw : qw;
    dh[i] = (h16)(w[i & 65535] * iv);
  } else {
    int base = (blk - 3072) * 4;
    int g = tid >> 6, l = tid & 63;
    int id = base + g;                     // sel*1024 + b*256 + n
    int n = id & 255, b = (id >> 8) & 3, sel = id >> 10;
    const float* w  = sel == 0 ? kw : sel == 1 ? vw : qw;
    const float* bb = sel == 0 ? kb : sel == 1 ? vb : qb;
    float s = 0.f;
    #pragma unroll
    for (int j = 0; j < 4; ++j) {
      int k = l*4 + j;
      float sm = stats[b*512 + k] * (1.f/T_);
      float s2 = stats[b*512 + 256 + k] * (1.f/T_);
      float iv = rsqrtf(fmaxf(s2 - sm*sm, 0.f) + 1e-5f);
      s += sm * iv * w[n*256 + k];
    }
    #pragma unroll
    for (int off = 32; off > 0; off >>= 1) s += __shfl_xor(s, off);
    if (l == 0) bias2[id] = bb[n] - s;
  }
}

// wf[bb][n,k] = sum_j ff1[n,j]*G[bb][j,k] + ff1[n,k]  -> hi-only plane.
__global__ __launch_bounds__(256) void mmrow_k(
    const float* __restrict__ A, const float* __restrict__ Bm,
    h16* __restrict__ dh)
{
  int n  = blockIdx.x & 255;
  int bb = blockIdx.x >> 8;
  __shared__ float Ar[256];
  int k = threadIdx.x;
  Ar[k] = A[n*256 + k];
  __syncthreads();
  const float* Bb = Bm + (size_t)bb*65536;
  float acc = 0.f;
  #pragma unroll 4
  for (int j = 0; j < 256; ++j) acc = fmaf(Ar[j], Bb[j*256 + k], acc);
  acc += Ar[k];
  dh[(size_t)bb*65536 + (size_t)n*256 + k] = (h16)acc;
}

// ============================================================================
// Pre-split fp16x2 MFMA GEMM, tile 128x128 (dual-A, dual-W, 3 MFMA).
// SGL=1: single-fp16 output. (r17-proven template.)
// ============================================================================
template<int ACT, int SGL>
__global__ __launch_bounds__(256, 2) void gemm_p(
    const h16* __restrict__ Agh, const h16* __restrict__ Agl,
    const h16* __restrict__ Wgh, const h16* __restrict__ Wgl,
    const float* __restrict__ bias,
    const h16* __restrict__ Rh, const h16* __restrict__ Rl,
    h16* __restrict__ Ch, h16* __restrict__ Cl,
    int K, size_t wbs)
{
  int b  = blockIdx.z;
  int n0 = blockIdx.x * 128;
  int t0 = blockIdx.y * 128;
  const h16* Ah_g = Agh + (size_t)b*T_*K;
  const h16* Al_g = Agl + (size_t)b*T_*K;
  const h16* Wh_g = Wgh + (size_t)b*wbs;
  const h16* Wl_g = Wgl + (size_t)b*wbs;
  __shared__ h16 S[16384];
  int tid = threadIdx.x, l = tid & 63, wid = tid >> 6;
  int wr = wid >> 1, wc = wid & 1, lr = l & 15, kg = l >> 4;
  f32x4 acc[4][4];
  #pragma unroll
  for (int m = 0; m < 4; ++m)
    #pragma unroll
    for (int n = 0; n < 4; ++n) acc[m][n] = (f32x4){0.f,0.f,0.f,0.f};

  for (int k0 = 0; k0 < K; k0 += 32) {
    #pragma unroll
    for (int i = 0; i < 8; ++i) {
      int c = i*256 + tid;
      int p = c >> 9, r = (c >> 2) & 127, kc = c & 3;
      int ks = k0 + ((kc ^ ((r >> 1) & 3)) << 3);
      const h16* src = (p == 0) ? Ah_g + (size_t)(t0 + r)*K + ks
                     : (p == 1) ? Al_g + (size_t)(t0 + r)*K + ks
                     : (p == 2) ? Wh_g + (size_t)(n0 + r)*K + ks
                                : Wl_g + (size_t)(n0 + r)*K + ks;
      gl2lds16(src, S + (size_t)c*8);
    }
    __syncthreads();
    half8 ah[4], al[4], wh[4], wl[4];
    #pragma unroll
    for (int m = 0; m < 4; ++m) {
      int row = wr*64 + m*16 + lr;
      int ko = (kg ^ ((row >> 1) & 3)) * 8;
      ah[m] = *(const half8*)&S[row*32 + ko];
      al[m] = *(const half8*)&S[4096 + row*32 + ko];
    }
    #pragma unroll
    for (int n = 0; n < 4; ++n) {
      int row = wc*64 + n*16 + lr;
      int ko = (kg ^ ((row >> 1) & 3)) * 8;
      wh[n] = *(const half8*)&S[8192 + row*32 + ko];
      wl[n] = *(const half8*)&S[12288 + row*32 + ko];
    }
    #pragma unroll
    for (int m = 0; m < 4; ++m)
      #pragma unroll
      for (int n = 0; n < 4; ++n) {
        acc[m][n] = __builtin_amdgcn_mfma_f32_16x16x32_f16(ah[m], wh[n], acc[m][n], 0, 0, 0);
        acc[m][n] = __builtin_amdgcn_mfma_f32_16x16x32_f16(al[m], wh[n], acc[m][n], 0, 0, 0);
        acc[m][n] = __builtin_amdgcn_mfma_f32_16x16x32_f16(ah[m], wl[n], acc[m][n], 0, 0, 0);
      }
    __syncthreads();
  }
  float* Sf = (float*)S;
  const int LS = 132;
  int erow = tid >> 3;
  int ecol = (tid & 7) * 16;
  #pragma unroll
  for (int m = 0; m < 4; ++m) {
    int lr0 = wr*16 + kg*4;
    #pragma unroll
    for (int n = 0; n < 4; ++n) {
      int lcol = wc*64 + n*16 + lr;
      Sf[(lr0+0)*LS + lcol] = acc[m][n][0];
      Sf[(lr0+1)*LS + lcol] = acc[m][n][1];
      Sf[(lr0+2)*LS + lcol] = acc[m][n][2];
      Sf[(lr0+3)*LS + lcol] = acc[m][n][3];
    }
    __syncthreads();
    int grow = t0 + (erow >> 4)*64 + m*16 + (erow & 15);
    size_t off = ((size_t)b*T_ + grow)*256 + n0 + ecol;
    float f[16];
    #pragma unroll
    for (int j = 0; j < 16; ++j) f[j] = Sf[erow*LS + ecol + j];
    #pragma unroll
    for (int j = 0; j < 16; ++j) {
      float v = f[j];
      if (bias) v += bias[n0 + ecol + j];
      if (ACT == 1) v = fmaxf(v, 0.f);
      if (ACT == 2) v = 1.f/(1.f + __expf(-v));
      if (ACT == 3) v = 0.5f*v*(1.f + erff(v*0.7071067811865475f));
      f[j] = v;
    }
    if (Rh) {
      half8 rh0 = *(const half8*)(Rh + off), rh1 = *(const half8*)(Rh + off + 8);
      half8 rl0 = *(const half8*)(Rl + off), rl1 = *(const half8*)(Rl + off + 8);
      #pragma unroll
      for (int j = 0; j < 8; ++j) { f[j] += join2(rh0[j], rl0[j]); f[j+8] += join2(rh1[j], rl1[j]); }
    }
    if (SGL) {
      half8 o0, o1;
      #pragma unroll
      for (int j = 0; j < 8; ++j) { o0[j] = (h16)f[j]; o1[j] = (h16)f[j+8]; }
      *(half8*)(Ch + off) = o0; *(half8*)(Ch + off + 8) = o1;
    } else {
      half8 oh0, ol0, oh1, ol1;
      #pragma unroll
      for (int j = 0; j < 8; ++j) {
        h16 hh = (h16)f[j];   oh0[j] = hh; ol0[j] = (h16)(f[j]   - (float)hh);
        h16 h2 = (h16)f[j+8]; oh1[j] = h2; ol1[j] = (h16)(f[j+8] - (float)h2);
      }
      *(half8*)(Ch + off) = oh0; *(half8*)(Ch + off + 8) = oh1;
      *(half8*)(Cl + off) = ol0; *(half8*)(Cl + off + 8) = ol1;
    }
    __syncthreads();
  }
}

// ============================================================================
// Standalone GEMM: A hi/lo, W hi only. BK=64: 12 chunks (48KB LDS), 4 MFMA
// per (m,n) per barrier -> K=256 in 4 barrier pairs. For SFI ff1/ff2.
// ============================================================================
template<int ACT>
__global__ __launch_bounds__(256, 2) void gemm_p_wh(
    const h16* __restrict__ Agh, const h16* __restrict__ Agl,
    const h16* __restrict__ Wg,
    const float* __restrict__ bias,
    const h16* __restrict__ Rh, const h16* __restrict__ Rl,
    h16* __restrict__ Ch, h16* __restrict__ Cl,
    size_t wbs)
{
  int b  = blockIdx.z;
  int n0 = blockIdx.x * 128;
  int t0 = blockIdx.y * 128;
  const h16* Ah_g = Agh + (size_t)b*T_*256;
  const h16* Al_g = Agl + (size_t)b*T_*256;
  const h16* W_g  = Wg + (size_t)b*wbs;
  __shared__ h16 S[24576];
  int tid = threadIdx.x, l = tid & 63, wid = tid >> 6;
  int wr = wid >> 1, wc = wid & 1, lr = l & 15, kg = l >> 4;
  f32x4 acc[4][4];
  #pragma unroll
  for (int m = 0; m < 4; ++m)
    #pragma unroll
    for (int n = 0; n < 4; ++n) acc[m][n] = (f32x4){0.f,0.f,0.f,0.f};

  for (int k0 = 0; k0 < 256; k0 += 64) {
    #pragma unroll
    for (int i = 0; i < 12; ++i) {
      int c = i*256 + tid;        // 0..3071
      int p = c >> 9, r = (c >> 2) & 127, kc = c & 3;
      int ks = k0 + (p & 1)*32 + ((kc ^ ((r >> 1) & 3)) << 3);
      const h16* src = (p < 2) ? Ah_g + (size_t)(t0 + r)*256 + ks
                     : (p < 4) ? Al_g + (size_t)(t0 + r)*256 + ks
                               : W_g  + (size_t)(n0 + r)*256 + ks;
      gl2lds16(src, S + (size_t)c*8);
    }
    __syncthreads();
    half8 a0[4], a1[4], l0[4], l1[4], w0[4], w1[4];
    #pragma unroll
    for (int m = 0; m < 4; ++m) {
      int row = wr*64 + m*16 + lr;
      int ko = (kg ^ ((row >> 1) & 3)) * 8;
      a0[m] = *(const half8*)&S[row*32 + ko];
      a1[m] = *(const half8*)&S[4096 + row*32 + ko];
      l0[m] = *(const half8*)&S[8192 + row*32 + ko];
      l1[m] = *(const half8*)&S[12288 + row*32 + ko];
    }
    #pragma unroll
    for (int n = 0; n < 4; ++n) {
      int row = wc*64 + n*16 + lr;
      int ko = (kg ^ ((row >> 1) & 3)) * 8;
      w0[n] = *(const half8*)&S[16384 + row*32 + ko];
      w1[n] = *(const half8*)&S[20480 + row*32 + ko];
    }
    #pragma unroll
    for (int m = 0; m < 4; ++m)
      #pragma unroll
      for (int n = 0; n < 4; ++n) {
        acc[m][n] = __builtin_amdgcn_mfma_f32_16x16x32_f16(a0[m], w0[n], acc[m][n], 0, 0, 0);
        acc[m][n] = __builtin_amdgcn_mfma_f32_16x16x32_f16(l0[m], w0[n], acc[m][n], 0, 0, 0);
        acc[m][n] = __builtin_amdgcn_mfma_f32_16x16x32_f16(a1[m], w1[n], acc[m][n], 0, 0, 0);
        acc[m][n] = __builtin_amdgcn_mfma_f32_16x16x32_f16(l1[m], w1[n], acc[m][n], 0, 0, 0);
      }
    __syncthreads();
  }
  float* Sf = (float*)S;
  const int LS = 132;
  int erow = tid >> 3;
  int ecol = (tid & 7) * 16;
  #pragma unroll
  for (int m = 0; m < 4; ++m) {
    int lr0 = wr*16 + kg*4;
    #pragma unroll
    for (int n = 0; n < 4; ++n) {
      int lcol = wc*64 + n*16 + lr;
      Sf[(lr0+0)*LS + lcol] = acc[m][n][0];
      Sf[(lr0+1)*LS + lcol] = acc[m][n][1];
      Sf[(lr0+2)*LS + lcol] = acc[m][n][2];
      Sf[(lr0+3)*LS + lcol] = acc[m][n][3];
    }
    __syncthreads();
    int grow = t0 + (erow >> 4)*64 + m*16 + (erow & 15);
    size_t off = ((size_t)b*T_ + grow)*256 + n0 + ecol;
    float f[16];
    #pragma unroll
    for (int j = 0; j < 16; ++j) {
      float v = Sf[erow*LS + ecol + j] + bias[n0 + ecol + j];
      if (ACT == 3) v = 0.5f*v*(1.f + erff(v*0.7071067811865475f));
      f[j] = v;
    }
    if (Rh) {
      half8 rh0 = *(const half8*)(Rh + off), rh1 = *(const half8*)(Rh + off + 8);
      half8 rl0 = *(const half8*)(Rl + off), rl1 = *(const half8*)(Rl + off + 8);
      #pragma unroll
      for (int j = 0; j < 8; ++j) { f[j] += join2(rh0[j], rl0[j]); f[j+8] += join2(rh1[j], rl1[j]); }
    }
    half8 oh0, ol0, oh1, ol1;
    #pragma unroll
    for (int j = 0; j < 8; ++j) {
      h16 hh = (h16)f[j];   oh0[j] = hh; ol0[j] = (h16)(f[j]   - (float)hh);
      h16 h2 = (h16)f[j+8]; oh1[j] = h2; ol1[j] = (h16)(f[j+8] - (float)h2);
    }
    *(half8*)(Ch + off) = oh0; *(half8*)(Ch + off + 8) = oh1;
    *(half8*)(Cl + off) = ol0; *(half8*)(Cl + off + 8) = ol1;
    __syncthreads();
  }
}

// ============================================================================
// Fused attention-out GEMM: out = [att|conv] @ Wcat(hi)^T + bias3 + fst.
// A single fp16 (two sources); W hi only. BK=64 (r21-proven).
// ============================================================================
__global__ __launch_bounds__(256, 2) void gemm_attout(
    const h16* __restrict__ A1f, const h16* __restrict__ A2f,
    const h16* __restrict__ Wg,
    const float* __restrict__ bias,
    const h16* __restrict__ Rh, const h16* __restrict__ Rl,
    h16* __restrict__ Ch, h16* __restrict__ Cl)
{
  int b  = blockIdx.z;
  int n0 = blockIdx.x * 128;
  int t0 = blockIdx.y * 128;
  size_t abase = (size_t)b*T_*256;
  __shared__ h16 S[16384];
  int tid = threadIdx.x, l = tid & 63, wid = tid >> 6;
  int wr = wid >> 1, wc = wid & 1, lr = l & 15, kg = l >> 4;
  f32x4 acc[4][4];
  #pragma unroll
  for (int m = 0; m < 4; ++m)
    #pragma unroll
    for (int n = 0; n < 4; ++n) acc[m][n] = (f32x4){0.f,0.f,0.f,0.f};

  for (int k0 = 0; k0 < 512; k0 += 64) {
    #pragma unroll
    for (int i = 0; i < 8; ++i) {
      int c = i*256 + tid;        // 0..2047
      int p = c >> 9, r = (c >> 2) & 127, kc = c & 3;
      int ks = k0 + (p & 1)*32 + ((kc ^ ((r >> 1) & 3)) << 3);
      const h16* src;
      if (p < 2) {
        if (ks < 256) src = A1f + abase + (size_t)(t0 + r)*256 + ks;
        else          src = A2f + abase + (size_t)(t0 + r)*256 + (ks - 256);
      } else {
        src = Wg + (size_t)(n0 + r)*512 + ks;
      }
      gl2lds16(src, S + (size_t)c*8);
    }
    __syncthreads();
    half8 a0[4], a1[4], w0[4], w1[4];
    #pragma unroll
    for (int m = 0; m < 4; ++m) {
      int row = wr*64 + m*16 + lr;
      int ko = (kg ^ ((row >> 1) & 3)) * 8;
      a0[m] = *(const half8*)&S[row*32 + ko];
      a1[m] = *(const half8*)&S[4096 + row*32 + ko];
    }
    #pragma unroll
    for (int n = 0; n < 4; ++n) {
      int row = wc*64 + n*16 + lr;
      int ko = (kg ^ ((row >> 1) & 3)) * 8;
      w0[n] = *(const half8*)&S[8192 + row*32 + ko];
      w1[n] = *(const half8*)&S[12288 + row*32 + ko];
    }
    #pragma unroll
    for (int m = 0; m < 4; ++m)
      #pragma unroll
      for (int n = 0; n < 4; ++n) {
        acc[m][n] = __builtin_amdgcn_mfma_f32_16x16x32_f16(a0[m], w0[n], acc[m][n], 0, 0, 0);
        acc[m][n] = __builtin_amdgcn_mfma_f32_16x16x32_f16(a1[m], w1[n], acc[m][n], 0, 0, 0);
      }
    __syncthreads();
  }
  float* Sf = (float*)S;
  const int LS = 132;
  int erow = tid >> 3;
  int ecol = (tid & 7) * 16;
  #pragma unroll
  for (int m = 0; m < 4; ++m) {
    int lr0 = wr*16 + kg*4;
    #pragma unroll
    for (int n = 0; n < 4; ++n) {
      int lcol = wc*64 + n*16 + lr;
      Sf[(lr0+0)*LS + lcol] = acc[m][n][0];
      Sf[(lr0+1)*LS + lcol] = acc[m][n][1];
      Sf[(lr0+2)*LS + lcol] = acc[m][n][2];
      Sf[(lr0+3)*LS + lcol] = acc[m][n][3];
    }
    __syncthreads();
    int grow = t0 + (erow >> 4)*64 + m*16 + (erow & 15);
    size_t off = ((size_t)b*T_ + grow)*256 + n0 + ecol;
    float f[16];
    #pragma unroll
    for (int j = 0; j < 16; ++j) f[j] = Sf[erow*LS + ecol + j] + bias[n0 + ecol + j];
    half8 rh0 = *(const half8*)(Rh + off), rh1 = *(const half8*)(Rh + off + 8);
    half8 rl0 = *(const half8*)(Rl + off), rl1 = *(const half8*)(Rl + off + 8);
    #pragma unroll
    for (int j = 0; j < 8; ++j) { f[j] += join2(rh0[j], rl0[j]); f[j+8] += join2(rh1[j], rl1[j]); }
    half8 oh0, ol0, oh1, ol1;
    #pragma unroll
    for (int j = 0; j < 8; ++j) {
      h16 hh = (h16)f[j];   oh0[j] = hh; ol0[j] = (h16)(f[j]   - (float)hh);
      h16 h2 = (h16)f[j+8]; oh1[j] = h2; ol1[j] = (h16)(f[j+8] - (float)h2);
    }
    *(half8*)(Ch + off) = oh0; *(half8*)(Ch + off + 8) = oh1;
    *(half8*)(Cl + off) = ol0; *(half8*)(Cl + off + 8) = ol1;
    __syncthreads();
  }
}

// ============================================================================
// Merged K/V/Q projection: A single, W' hi only. BK=64 (r21-proven).
// XCD-swizzled flat grid 1536, 2 blocks/CU.
// ============================================================================
__global__ __launch_bounds__(256, 2) void gemm_qkv(
    const h16* __restrict__ Af, const h16* __restrict__ Wqkv,
    const float* __restrict__ bias2,
    h16* __restrict__ Kf, h16* __restrict__ Vf, h16* __restrict__ Qf)
{
  int fid = blockIdx.x;
  int swz = (fid & 7)*192 + (fid >> 3);
  int xsel = swz % 6;
  int sel = xsel >> 1;
  int n0  = (xsel & 1) * 128;
  int t0  = ((swz / 6) & 63) * 128;
  int b   = swz / 384;
  const h16* A_g = Af + (size_t)b*T_*256;
  const h16* W_g = Wqkv + (size_t)(sel*4 + b)*65536;
  const float* bias = bias2 + (size_t)(sel*4 + b)*256;
  h16* dst = sel == 0 ? Kf : sel == 1 ? Vf : Qf;
  __shared__ h16 S[16384];
  int tid = threadIdx.x, l = tid & 63, wid = tid >> 6;
  int wr = wid >> 1, wc = wid & 1, lr = l & 15, kg = l >> 4;
  f32x4 acc[4][4];
  #pragma unroll
  for (int m = 0; m < 4; ++m)
    #pragma unroll
    for (int n = 0; n < 4; ++n) acc[m][n] = (f32x4){0.f,0.f,0.f,0.f};

  for (int k0 = 0; k0 < 256; k0 += 64) {
    #pragma unroll
    for (int i = 0; i < 8; ++i) {
      int c = i*256 + tid;        // 0..2047
      int p = c >> 9, r = (c >> 2) & 127, kc = c & 3;
      int ks = k0 + (p & 1)*32 + ((kc ^ ((r >> 1) & 3)) << 3);
      const h16* src = (p < 2) ? A_g + (size_t)(t0 + r)*256 + ks
                               : W_g + (size_t)(n0 + r)*256 + ks;
      gl2lds16(src, S + (size_t)c*8);
    }
    __syncthreads();
    half8 a0[4], a1[4], w0[4], w1[4];
    #pragma unroll
    for (int m = 0; m < 4; ++m) {
      int row = wr*64 + m*16 + lr;
      int ko = (kg ^ ((row >> 1) & 3)) * 8;
      a0[m] = *(const half8*)&S[row*32 + ko];
      a1[m] = *(const half8*)&S[4096 + row*32 + ko];
    }
    #pragma unroll
    for (int n = 0; n < 4; ++n) {
      int row = wc*64 + n*16 + lr;
      int ko = (kg ^ ((row >> 1) & 3)) * 8;
      w0[n] = *(const half8*)&S[8192 + row*32 + ko];
      w1[n] = *(const half8*)&S[12288 + row*32 + ko];
    }
    #pragma unroll
    for (int m = 0; m < 4; ++m)
      #pragma unroll
      for (int n = 0; n < 4; ++n) {
        acc[m][n] = __builtin_amdgcn_mfma_f32_16x16x32_f16(a0[m], w0[n], acc[m][n], 0, 0, 0);
        acc[m][n] = __builtin_amdgcn_mfma_f32_16x16x32_f16(a1[m], w1[n], acc[m][n], 0, 0, 0);
      }
    __syncthreads();
  }
  float* Sf = (float*)S;
  const int LS = 132;
  int erow = tid >> 3;
  int ecol = (tid & 7) * 16;
  #pragma unroll
  for (int m = 0; m < 4; ++m) {
    int lr0 = wr*16 + kg*4;
    #pragma unroll
    for (int n = 0; n < 4; ++n) {
      int lcol = wc*64 + n*16 + lr;
      Sf[(lr0+0)*LS + lcol] = acc[m][n][0];
      Sf[(lr0+1)*LS + lcol] = acc[m][n][1];
      Sf[(lr0+2)*LS + lcol] = acc[m][n][2];
      Sf[(lr0+3)*LS + lcol] = acc[m][n][3];
    }
    __syncthreads();
    int grow = t0 + (erow >> 4)*64 + m*16 + (erow & 15);
    size_t off = ((size_t)b*T_ + grow)*256 + n0 + ecol;
    half8 o0, o1;
    #pragma unroll
    for (int j = 0; j < 8; ++j) {
      float v0 = Sf[erow*LS + ecol + j]     + bias[n0 + ecol + j];
      float v1 = Sf[erow*LS + ecol + 8 + j] + bias[n0 + ecol + 8 + j];
      if (sel != 1) {
        v0 = 1.f/(1.f + __expf(-v0));
        v1 = 1.f/(1.f + __expf(-v1));
      }
      o0[j] = (h16)v0; o1[j] = (h16)v1;
    }
    *(half8*)(dst + off) = o0; *(half8*)(dst + off + 8) = o1;
    __syncthreads();
  }
}

// ============================================================================
// Dilated conv: 3-tap MFMA GEMM + fused stats. A hi only, W hi only.
// BK=64 (r21-proven). Output single fp16. XCD-swizzled flat grid 512.
// ============================================================================
__global__ __launch_bounds__(256, 2) void conv_p(
    const h16* __restrict__ Agh,
    const h16* __restrict__ Wg,
    const float* __restrict__ bias,
    h16* __restrict__ Cf,
    float* __restrict__ stats, const float* __restrict__ zbuf, int dil)
{
  int fid = blockIdx.x;
  int swz = (fid & 7)*64 + (fid >> 3);
  int n0 = (swz & 1) * 128;
  int t0 = ((swz >> 1) & 63) * 128;
  int b  = swz >> 7;
  const h16* Ah_g = Agh + (size_t)b*T_*256;
  __shared__ h16 S[16384];
  __shared__ float cstat[2][128];
  int tid = threadIdx.x, l = tid & 63, wid = tid >> 6;
  int wr = wid >> 1, wc = wid & 1, lr = l & 15, kg = l >> 4;
  f32x4 acc[4][4];
  #pragma unroll
  for (int m = 0; m < 4; ++m)
    #pragma unroll
    for (int n = 0; n < 4; ++n) acc[m][n] = (f32x4){0.f,0.f,0.f,0.f};

  for (int tap = 0; tap < 3; ++tap) {
    int off = (tap - 1) * dil;
    const h16* W_t = Wg + (size_t)tap*65536;
    for (int k0 = 0; k0 < 256; k0 += 64) {
      #pragma unroll
      for (int i = 0; i < 8; ++i) {
        int c = i*256 + tid;        // 0..2047
        int p = c >> 9, r = (c >> 2) & 127, kc = c & 3;
        int ks = k0 + (p & 1)*32 + ((kc ^ ((r >> 1) & 3)) << 3);
        const h16* src;
        if (p < 2) {
          int rt = t0 + r + off;
          if ((unsigned)rt < (unsigned)T_)
            src = Ah_g + (size_t)rt*256 + ks;
          else
            src = (const h16*)zbuf;
        } else {
          src = W_t + (size_t)(n0 + r)*256 + ks;
        }
        gl2lds16(src, S + (size_t)c*8);
      }
      __syncthreads();
      half8 a0[4], a1[4], w0[4], w1[4];
      #pragma unroll
      for (int m = 0; m < 4; ++m) {
        int row = wr*64 + m*16 + lr;
        int ko = (kg ^ ((row >> 1) & 3)) * 8;
        a0[m] = *(const half8*)&S[row*32 + ko];
        a1[m] = *(const half8*)&S[4096 + row*32 + ko];
      }
      #pragma unroll
      for (int n = 0; n < 4; ++n) {
        int row = wc*64 + n*16 + lr;
        int ko = (kg ^ ((row >> 1) & 3)) * 8;
        w0[n] = *(const half8*)&S[8192 + row*32 + ko];
        w1[n] = *(const half8*)&S[12288 + row*32 + ko];
      }
      #pragma unroll
      for (int m = 0; m < 4; ++m)
        #pragma unroll
        for (int n = 0; n < 4; ++n) {
          acc[m][n] = __builtin_amdgcn_mfma_f32_16x16x32_f16(a0[m], w0[n], acc[m][n], 0, 0, 0);
          acc[m][n] = __builtin_amdgcn_mfma_f32_16x16x32_f16(a1[m], w1[n], acc[m][n], 0, 0, 0);
        }
      __syncthreads();
    }
  }
  cstat[tid >> 7][tid & 127] = 0.f;
  __syncthreads();
  #pragma unroll
  for (int n = 0; n < 4; ++n) {
    int cl = wc*64 + n*16 + lr;
    float bi = bias[n0 + cl];
    float s = 0.f, s2 = 0.f;
    #pragma unroll
    for (int m = 0; m < 4; ++m)
      #pragma unroll
      for (int r = 0; r < 4; ++r) {
        float v = fmaxf(acc[m][n][r] + bi, 0.f);
        acc[m][n][r] = v;
        s += v; s2 += v*v;
      }
    atomicAdd(&cstat[0][cl], s);
    atomicAdd(&cstat[1][cl], s2);
  }
  __syncthreads();
  if (tid < 128)      atomicAdd(&stats[b*512 + n0 + tid], cstat[0][tid]);
  else if (tid < 256) atomicAdd(&stats[b*512 + 256 + n0 + (tid-128)], cstat[1][tid-128]);
  __syncthreads();
  float* Sf = (float*)S;
  const int LS = 132;
  int erow = tid >> 3;
  int ecol = (tid & 7) * 16;
  #pragma unroll
  for (int m = 0; m < 4; ++m) {
    int lr0 = wr*16 + kg*4;
    #pragma unroll
    for (int n = 0; n < 4; ++n) {
      int lcol = wc*64 + n*16 + lr;
      Sf[(lr0+0)*LS + lcol] = acc[m][n][0];
      Sf[(lr0+1)*LS + lcol] = acc[m][n][1];
      Sf[(lr0+2)*LS + lcol] = acc[m][n][2];
      Sf[(lr0+3)*LS + lcol] = acc[m][n][3];
    }
    __syncthreads();
    int grow = t0 + (erow >> 4)*64 + m*16 + (erow & 15);
    size_t off2 = ((size_t)b*T_ + grow)*256 + n0 + ecol;
    half8 o0, o1;
    #pragma unroll
    for (int j = 0; j < 8; ++j) {
      o0[j] = (h16)Sf[erow*LS + ecol + j];
      o1[j] = (h16)Sf[erow*LS + ecol + 8 + j];
    }
    *(half8*)(Cf + off2) = o0; *(half8*)(Cf + off2 + 8) = o1;
    __syncthreads();
  }
}

// ============================================================================
// kv partial via MFMA (gram-style transposed staging): KV[d][e] =
// sum_t K[t][d] V[t][e], plus ksum[d]. grid (16,16), K=512 per block.
// ============================================================================
__global__ __launch_bounds__(256) void kv_part_p(
    const h16* __restrict__ Kf, const h16* __restrict__ Vf,
    float* __restrict__ pkv)
{
  int bh = blockIdx.y, b = bh >> 2, h = bh & 3;
  int t0 = blockIdx.x * 512;
  __shared__ h16 S[2][64][64];
  __shared__ float ksum[64];
  int tid = threadIdx.x, l = tid & 63, wid = tid >> 6;
  int lr = l & 15, kg = l >> 4;
  if (tid < 64) ksum[tid] = 0.f;
  float ksp[8] = {};
  f32x4 acc[4];
  #pragma unroll
  for (int n = 0; n < 4; ++n) acc[n] = (f32x4){0.f,0.f,0.f,0.f};

  for (int k0 = 0; k0 < 512; k0 += 64) {
    __syncthreads();
    #pragma unroll
    for (int i = 0; i < 2; ++i) {
      int q = tid + i*256;          // 0..511
      int tt = q >> 3;              // 0..63
      int c8 = (q & 7) * 8;         // 0..56
      size_t row = ((size_t)b*T_ + t0 + k0 + tt)*256 + h*64;
      half8 k8 = *(const half8*)(Kf + row + c8);
      half8 v8 = *(const half8*)(Vf + row + c8);
      int ts = tt ^ ((q & 3) << 3);
      #pragma unroll
      for (int j = 0; j < 8; ++j) {
        S[0][c8+j][ts] = k8[j];
        S[1][c8+j][ts] = v8[j];
        ksp[j] += (float)k8[j];
      }
    }
    __syncthreads();
    half8 a0, a1, b0[4], b1[4];
    {
      int row = wid*16 + lr;
      int ko = (kg*8) ^ (((row >> 3) & 3) << 3);
      a0 = *(const half8*)&S[0][row][ko];
      a1 = *(const half8*)&S[0][row][32 + ko];
    }
    #pragma unroll
    for (int n = 0; n < 4; ++n) {
      int row = n*16 + lr;
      int ko = (kg*8) ^ (((row >> 3) & 3) << 3);
      b0[n] = *(const half8*)&S[1][row][ko];
      b1[n] = *(const half8*)&S[1][row][32 + ko];
    }
    #pragma unroll
    for (int n = 0; n < 4; ++n) {
      acc[n] = __builtin_amdgcn_mfma_f32_16x16x32_f16(a0, b0[n], acc[n], 0, 0, 0);
      acc[n] = __builtin_amdgcn_mfma_f32_16x16x32_f16(a1, b1[n], acc[n], 0, 0, 0);
    }
  }
  __syncthreads();
  {
    int dbase = (tid & 7) * 8;
    #pragma unroll
    for (int j = 0; j < 8; ++j) atomicAdd(&ksum[dbase + j], ksp[j]);
  }
  __syncthreads();
  float* dst = pkv + ((size_t)blockIdx.x*16 + bh)*4160;
  #pragma unroll
  for (int n = 0; n < 4; ++n) {
    int e = n*16 + lr;
    #pragma unroll
    for (int r = 0; r < 4; ++r) {
      int d = wid*16 + kg*4 + r;
      dst[d*64 + e] = acc[n][r];
    }
  }
  if (tid < 64) dst[4096 + tid] = ksum[tid];
}

__global__ __launch_bounds__(256) void kv_final_k(
    const float* __restrict__ pkv, float* __restrict__ kv)
{
  int bh = blockIdx.x;
  for (int idx = threadIdx.x; idx < 4160; idx += 256) {
    float s = 0.f;
    #pragma unroll
    for (int c = 0; c < 16; ++c) s += pkv[((size_t)c*16 + bh)*4160 + idx];
    kv[(size_t)bh*4160 + idx] = s;
  }
}

// ============================================================================
// att apply; Q single fp16 in, O single fp16 out (may alias Q).
// ============================================================================
__global__ __launch_bounds__(256) void att_apply_p(
    const h16* __restrict__ Qf, const float* __restrict__ kv,
    h16* __restrict__ Of)
{
  int bh = blockIdx.y, b = bh >> 2, h = bh & 3;
  int t0 = blockIdx.x * 128;
  __shared__ float QsT[64][132];
  __shared__ float KVs[64][68];
  __shared__ float ks[64];
  int tid = threadIdx.x;
  const float* src = kv + (size_t)bh*4160;
  #pragma unroll
  for (int i = 0; i < 16; ++i) {
    int idx = tid + i*256;
    KVs[idx >> 6][idx & 63] = src[idx];
  }
  if (tid < 64) ks[tid] = src[4096 + tid] + 1e-6f;
  #pragma unroll
  for (int i = 0; i < 4; ++i) {
    int q8 = tid + i*256;
    int t  = q8 >> 3;
    int d8 = (q8 & 7) * 8;
    size_t off = ((size_t)b*T_ + t0 + t)*256 + h*64 + d8;
    half8 qh = *(const half8*)(Qf + off);
    #pragma unroll
    for (int j = 0; j < 8; ++j) QsT[d8+j][t] = (float)qh[j];
  }
  __syncthreads();
  int t2 = (tid >> 2) * 2;
  int e0 = (tid & 3) * 16;
  float acc[2][16] = {};
  float den[2] = {};
  for (int dd = 0; dd < 64; ++dd) {
    float2 q = *(const float2*)&QsT[dd][t2];
    float kd = ks[dd];
    den[0] = fmaf(q.x, kd, den[0]);
    den[1] = fmaf(q.y, kd, den[1]);
    float va[16];
    *(float4*)&va[0]  = *(const float4*)&KVs[dd][e0+0];
    *(float4*)&va[4]  = *(const float4*)&KVs[dd][e0+4];
    *(float4*)&va[8]  = *(const float4*)&KVs[dd][e0+8];
    *(float4*)&va[12] = *(const float4*)&KVs[dd][e0+12];
    #pragma unroll
    for (int j = 0; j < 16; ++j) {
      acc[0][j] = fmaf(q.x, va[j], acc[0][j]);
      acc[1][j] = fmaf(q.y, va[j], acc[1][j]);
    }
  }
  #pragma unroll
  for (int ti = 0; ti < 2; ++ti) {
    float z = 1.f / den[ti];
    size_t off = ((size_t)b*T_ + t0 + t2 + ti)*256 + h*64 + e0;
    half8 v0, v1;
    #pragma unroll
    for (int j = 0; j < 8; ++j) {
      v0[j] = (h16)(acc[ti][j] * z);
      v1[j] = (h16)(acc[ti][j+8] * z);
    }
    *(half8*)(Of + off) = v0;
    *(half8*)(Of + off + 8) = v1;
  }
}

// ============================================================================
// SFI gram partial: A (fsc single) x B (fst hi). BK=64 transposed staging,
// 2 MFMA per (m,n) per barrier -> 4 barrier pairs. grid (32,4,B).
// ============================================================================
__global__ __launch_bounds__(256, 2) void gram_part_p(
    const h16* __restrict__ Af, const h16* __restrict__ Bf,
    float* __restrict__ pg)
{
  int b = blockIdx.z;
  int quad = blockIdx.y;
  int slab = blockIdx.x;
  int c0 = (quad >> 1) * 128, d0 = (quad & 1) * 128;
  int t0 = slab * 256;
  __shared__ h16 S[2][128][64];
  int tid = threadIdx.x, l = tid & 63, wid = tid >> 6;
  int wr = wid >> 1, wc = wid & 1, lr = l & 15, kg = l >> 4;
  f32x4 acc[4][4];
  #pragma unroll
  for (int m = 0; m < 4; ++m)
    #pragma unroll
    for (int n = 0; n < 4; ++n) acc[m][n] = (f32x4){0.f,0.f,0.f,0.f};

  for (int k0 = 0; k0 < 256; k0 += 64) {
    #pragma unroll
    for (int i = 0; i < 4; ++i) {
      int q = tid + i*256;        // 0..1023
      int tt = q >> 4;            // 0..63
      int c8 = (q & 15) * 8;
      size_t row = ((size_t)b*T_ + t0 + k0 + tt) * 256;
      half8 a8 = *(const half8*)(Af + row + c0 + c8);
      half8 b8 = *(const half8*)(Bf + row + d0 + c8);
      int ts = tt ^ ((q & 3) << 3);
      #pragma unroll
      for (int j = 0; j < 8; ++j) {
        S[0][c8+j][ts] = a8[j];
        S[1][c8+j][ts] = b8[j];
      }
    }
    __syncthreads();
    half8 a0[4], a1[4], b0[4], b1[4];
    #pragma unroll
    for (int m = 0; m < 4; ++m) {
      int row = wr*64 + m*16 + lr;
      int ko = (kg*8) ^ (((row >> 3) & 3) << 3);
      a0[m] = *(const half8*)&S[0][row][ko];
      a1[m] = *(const half8*)&S[0][row][32 + ko];
    }
    #pragma unroll
    for (int n = 0; n < 4; ++n) {
      int row = wc*64 + n*16 + lr;
      int ko = (kg*8) ^ (((row >> 3) & 3) << 3);
      b0[n] = *(const half8*)&S[1][row][ko];
      b1[n] = *(const half8*)&S[1][row][32 + ko];
    }
    #pragma unroll
    for (int m = 0; m < 4; ++m)
      #pragma unroll
      for (int n = 0; n < 4; ++n) {
        acc[m][n] = __builtin_amdgcn_mfma_f32_16x16x32_f16(a0[m], b0[n], acc[m][n], 0, 0, 0);
        acc[m][n] = __builtin_amdgcn_mfma_f32_16x16x32_f16(a1[m], b1[n], acc[m][n], 0, 0, 0);
      }
    __syncthreads();
  }
  float* dst = pg + ((size_t)(slab*B_ + b)*4 + quad)*16384;
  #pragma unroll
  for (int m = 0; m < 4; ++m)
    #pragma unroll
    for (int n = 0; n < 4; ++n) {
      int cl = wr*64 + m*16 + kg*4;
      int dl = wc*64 + n*16 + lr;
      #pragma unroll
      for (int r = 0; r < 4; ++r)
        dst[(size_t)(cl + r)*128 + dl] = acc[m][n][r];
    }
}

// reduce 32 slabs + softmax(G/T) per row -> f32 G. grid (B*256), 64 thr.
__global__ __launch_bounds__(64) void gram_smax_p(
    const float* __restrict__ pg, float* __restrict__ G)
{
  int row = blockIdx.x;
  int b = row >> 8, c = row & 255;
  int l = threadIdx.x;
  int d4 = l * 4;
  int quad = ((c >= 128) ? 2 : 0) | ((d4 >= 128) ? 1 : 0);
  size_t base = ((size_t)b*4 + quad)*16384 + (size_t)(c & 127)*128 + (d4 & 127);
  float s0 = 0.f, s1 = 0.f, s2 = 0.f, s3 = 0.f;
  for (int sl = 0; sl < 32; ++sl) {
    const float* p = pg + (size_t)sl*(B_*4*16384) + base;
    float4 v = *(const float4*)p;
    s0 += v.x; s1 += v.y; s2 += v.z; s3 += v.w;
  }
  float v[4] = {s0*(1.f/T_), s1*(1.f/T_), s2*(1.f/T_), s3*(1.f/T_)};
  float mx = fmaxf(fmaxf(v[0], v[1]), fmaxf(v[2], v[3]));
  #pragma unroll
  for (int off = 32; off > 0; off >>= 1) mx = fmaxf(mx, __shfl_xor(mx, off));
  float s = 0.f;
  #pragma unroll
  for (int j = 0; j < 4; ++j) { v[j] = __expf(v[j] - mx); s += v[j]; }
  #pragma unroll
  for (int off = 32; off > 0; off >>= 1) s += __shfl_xor(s, off);
  float inv = 1.f / s;
  float4 o = make_float4(v[0]*inv, v[1]*inv, v[2]*inv, v[3]*inv);
  *(float4*)(G + (size_t)b*65536 + (size_t)c*256 + d4) = o;
}

// ============================================================================
// Final as MFMA GEMM: out[b,o,t] = ((fst . W[o]) + bn[o]) * mask.
// ============================================================================
__global__ __launch_bounds__(256, 2) void gemm_out(
    const h16* __restrict__ Agh, const h16* __restrict__ Agl,
    const h16* __restrict__ Wgh, const h16* __restrict__ Wgl,
    const float* __restrict__ bn, const float* __restrict__ mask,
    float* __restrict__ out)
{
  int bt0 = blockIdx.x * 256;
  int b = bt0 >> 13;
  __shared__ h16 S[20480];
  int tid = threadIdx.x, l = tid & 63, wid = tid >> 6;
  int lr = l & 15, kg = l >> 4;
  f32x4 acc[4][4];
  #pragma unroll
  for (int m = 0; m < 4; ++m)
    #pragma unroll
    for (int n = 0; n < 4; ++n) acc[m][n] = (f32x4){0.f,0.f,0.f,0.f};

  for (int k0 = 0; k0 < 256; k0 += 32) {
    #pragma unroll
    for (int i = 0; i < 10; ++i) {
      int c = i*256 + tid;
      const h16* src;
      if (c < 2048) {
        int p = c >> 10, rem = c & 1023, r = rem >> 2, kc = rem & 3;
        int ks = k0 + ((kc ^ ((r >> 1) & 3)) << 3);
        src = (p ? Agl : Agh) + (size_t)(bt0 + r)*256 + ks;
      } else {
        int c2 = c - 2048;
        int p = c2 >> 8, rem = c2 & 255, r = rem >> 2, kc = rem & 3;
        int ks = k0 + ((kc ^ ((r >> 1) & 3)) << 3);
        src = (p ? Wgl : Wgh) + (size_t)r*256 + ks;
      }
      gl2lds16(src, S + (size_t)c*8);
    }
    __syncthreads();
    half8 ah[4], al[4], wh[4], wl[4];
    #pragma unroll
    for (int m = 0; m < 4; ++m) {
      int row = wid*64 + m*16 + lr;
      int ko = ((kg ^ ((row >> 1) & 3)) << 3);
      ah[m] = *(const half8*)&S[row*32 + ko];
      al[m] = *(const half8*)&S[8192 + row*32 + ko];
    }
    #pragma unroll
    for (int n = 0; n < 4; ++n) {
      int row = n*16 + lr;
      int ko = ((kg ^ ((row >> 1) & 3)) << 3);
      wh[n] = *(const half8*)&S[16384 + row*32 + ko];
      wl[n] = *(const half8*)&S[18432 + row*32 + ko];
    }
    #pragma unroll
    for (int m = 0; m < 4; ++m)
      #pragma unroll
      for (int n = 0; n < 4; ++n) {
        acc[m][n] = __builtin_amdgcn_mfma_f32_16x16x32_f16(ah[m], wh[n], acc[m][n], 0, 0, 0);
        acc[m][n] = __builtin_amdgcn_mfma_f32_16x16x32_f16(al[m], wh[n], acc[m][n], 0, 0, 0);
        acc[m][n] = __builtin_amdgcn_mfma_f32_16x16x32_f16(ah[m], wl[n], acc[m][n], 0, 0, 0);
      }
    __syncthreads();
  }
  #pragma unroll
  for (int m = 0; m < 4; ++m)
    #pragma unroll
    for (int n = 0; n < 4; ++n) {
      int col = n*16 + lr;
      if (col < 48) {
        float bi = bn[col];
        #pragma unroll
        for (int r = 0; r < 4; ++r) {
          int grow = bt0 + wid*64 + m*16 + kg*4 + r;
          int t = grow & (T_ - 1);
          out[((size_t)b*48 + col)*T_ + t] =
              (acc[m][n][r] + bi) * mask[(size_t)b*T_ + t];
        }
      }
    }
}

// ============================================================================
extern "C" void kernel_launch(void* const* d_in, const int* in_sizes, int n_in,
                              void* d_out, int out_size, void* d_ws, size_t ws_size,
                              hipStream_t stream) {
  const float* x         = (const float*)d_in[0];
  const float* mask      = (const float*)d_in[1];
  const float* conv_in_w = (const float*)d_in[2];
  const float* conv_in_b = (const float*)d_in[3];
  const float* conv_t_w  = (const float*)d_in[4];
  const float* conv_t_b  = (const float*)d_in[5];
  const float* sfi_cs_w  = (const float*)d_in[6];
  const float* sfi_cs_b  = (const float*)d_in[7];
  const float* sfi_ff1_w = (const float*)d_in[8];
  const float* sfi_ff1_b = (const float*)d_in[9];
  const float* sfi_ff2_w = (const float*)d_in[10];
  const float* sfi_ff2_b = (const float*)d_in[11];
  const float* ff_w      = (const float*)d_in[12];
  const float* ff_b      = (const float*)d_in[13];
  const float* qw = (const float*)d_in[14]; const float* qb = (const float*)d_in[15];
  const float* kw = (const float*)d_in[16]; const float* kb = (const float*)d_in[17];
  const float* vw = (const float*)d_in[18]; const float* vb = (const float*)d_in[19];
  const float* ow = (const float*)d_in[20]; const float* ob = (const float*)d_in[21];
  const float* co_w = (const float*)d_in[22]; const float* co_b = (const float*)d_in[23];
  const float* out_w = (const float*)d_in[24]; const float* out_b = (const float*)d_in[25];

  float* ws = (float*)d_ws;
  const size_t BT = (size_t)B_ * T_;
  const size_t NB = BT * 256;
  float* smallR = ws;                        // BT*64 f32
  float* bigR   = smallR + BT*64;            // 5 * NB
  float* GR     = bigR + 5*NB;               // B*65536 f32
  float* statsR = GR + (size_t)B_*65536;     // B*512
  float* kvR    = statsR + (size_t)B_*512;   // 16*4160
  float* wsfiR  = kvR + 16*4160;             // 147456
  float* zbufR  = wsfiR + 147456;            // 16 floats

  h16* small_h = (h16*)smallR; h16* small_l = small_h + BT*64;
  h16 *bigH[5], *bigL[5];
  for (int i = 0; i < 5; ++i) { bigH[i] = (h16*)(bigR + (size_t)i*NB); bigL[i] = bigH[i] + NB; }
  float* Gf    = GR;
  float* stats = statsR;
  float* kvbuf = kvR;
  h16* wsfi_h = (h16*)wsfiR; h16* wsfi_l = wsfi_h + 147456;
  float* pkv   = smallR;
  h16* wqkv   = (h16*)smallR;                // 786432 elems (hi only)
  h16* wf_h    = (h16*)smallR;               // 262144 elems (SFI only, hi only)
  h16* wlay   = (h16*)(smallR + 1064960);    // 327680 elems (hi only)
  float* bias2 = smallR + 1392640;           // 3072 f32
  float* bias3 = smallR + 1395712;           // 256 f32

  dim3 gh(2, T_/128, B_);
  dim3 b256(256);

  hipMemsetAsync(zbufR, 0, 64, stream);
  init_fs_k<<<dim3((unsigned)(BT*64/256)), b256, 0, stream>>>(x, conv_in_w, conv_in_b, small_h, small_l, 4);
  wsplit_k<<<dim3(64), b256, 0, stream>>>(conv_t_w, wsfi_h, wsfi_l, 16384);
  gemm_p<0,0><<<gh, b256, 0, stream>>>(small_h, small_l, wsfi_h, wsfi_l, conv_t_b,
                                       nullptr, nullptr, bigH[0], bigL[0], 64, 0);

  int ifst = 0;
  int fr[4] = {1, 2, 3, 4};
  int count = 0;
  for (int i = 0; i < 10; ++i) {
    if (i == 1 || i == 3 || i == 5 || i == 7) {
      // ---- SFI ----
      int a = fr[0], bb = fr[1], c = fr[2], d = fr[3];
      sprep_k<<<dim3(576), b256, 0, stream>>>(sfi_ff1_w + (size_t)count*65536,
                                              sfi_ff2_w + (size_t)count*65536,
                                              sfi_cs_w + (size_t)count*16384,
                                              wsfi_h, wsfi_l);
      init_fs_k<<<dim3((unsigned)(BT*64/256)), b256, 0, stream>>>(x, conv_in_w, conv_in_b, small_h, small_l, count);
      // fsc -> bigH[a] single fp16
      gemm_p<0,1><<<gh, b256, 0, stream>>>(small_h, small_l, wsfi_h + 131072, wsfi_l + 131072,
                                           sfi_cs_b + count*256, nullptr, nullptr,
                                           bigH[a], nullptr, 64, 0);
      float* pgram = bigR + (size_t)bb*NB;
      gram_part_p<<<dim3(32, 4, B_), b256, 0, stream>>>(bigH[a], bigH[ifst], pgram);
      gram_smax_p<<<dim3(B_*256), dim3(64), 0, stream>>>(pgram, Gf);
      mmrow_k<<<dim3(B_*256), b256, 0, stream>>>(sfi_ff1_w + (size_t)count*65536, Gf, wf_h);
      // ff1: W hi-only (wf, per-batch), A = fst hi/lo, gelu
      gemm_p_wh<3><<<gh, b256, 0, stream>>>(bigH[ifst], bigL[ifst], wf_h,
                                            sfi_ff1_b + count*256, nullptr, nullptr,
                                            bigH[c], bigL[c], 65536);
      // ff2: W hi-only (wsfi hi), A hi/lo, + fst residual
      gemm_p_wh<0><<<gh, b256, 0, stream>>>(bigH[c], bigL[c], wsfi_h + 65536,
                                            sfi_ff2_b + count*256, bigH[ifst], bigL[ifst],
                                            bigH[d], bigL[d], 0);
      fr[0] = a; fr[1] = bb; fr[2] = c; fr[3] = ifst;
      ifst = d;
      ++count;
    }
    // ---- attention module ----
    int a = fr[0], bb = fr[1], c = fr[2], d = fr[3];
    int dil = 1 << i;
    prep_layer_k<<<dim3(1289), b256, 0, stream>>>(ff_w + (size_t)i*196608,
                                                  co_w + (size_t)i*65536,
                                                  ow + (size_t)i*65536, ob + i*256,
                                                  co_b + i*256,
                                                  wlay, bias3, stats);
    // conv: A hi only, W hi only -> single fp16
    conv_p<<<dim3(512), b256, 0, stream>>>(bigH[ifst], wlay, ff_b + i*256,
                                           bigH[a], stats, zbufR, dil);
    nwnb_k<<<dim3(3840), b256, 0, stream>>>(qw + (size_t)i*65536, kw + (size_t)i*65536,
                                            vw + (size_t)i*65536,
                                            qb + i*256, kb + i*256, vb + i*256,
                                            stats, wqkv, bias2);
    gemm_qkv<<<dim3(1536), b256, 0, stream>>>(bigH[a], wqkv, bias2,
                                              bigH[bb], bigH[c], bigH[d]);
    kv_part_p<<<dim3(16, 16), b256, 0, stream>>>(bigH[bb], bigH[c], pkv);
    kv_final_k<<<dim3(16), b256, 0, stream>>>(pkv, kvbuf);
    att_apply_p<<<dim3(T_/128, 16), b256, 0, stream>>>(bigH[d], kvbuf, bigH[d]);
    gemm_attout<<<gh, b256, 0, stream>>>(bigH[d], bigH[a],
                                         wlay + 196608, bias3,
                                         bigH[ifst], bigL[ifst], bigH[bb], bigL[bb]);
    fr[0] = a; fr[1] = c; fr[2] = d; fr[3] = ifst;
    ifst = bb;
  }
  wsplit_out_k<<<dim3(64), b256, 0, stream>>>(out_w, wsfi_h, wsfi_l);
  gemm_out<<<dim3((unsigned)(BT/256)), b256, 0, stream>>>(bigH[ifst], bigL[ifst], wsfi_h, wsfi_l,
                                                          out_b, mask, (float*)d_out);
}